// Round 5
// baseline (243.867 us; speedup 1.0000x reference)
//
#include <hip/hip_runtime.h>

// ---------------- types ----------------
typedef __bf16 bf16;
typedef __bf16 bf16x4 __attribute__((ext_vector_type(4)));
typedef __bf16 bf16x8 __attribute__((ext_vector_type(8)));
typedef float f32x4 __attribute__((ext_vector_type(4)));
typedef unsigned u32x4 __attribute__((ext_vector_type(4)));

#define AS1C(p) ((const __attribute__((address_space(1))) void*)(p))
#define AS3(p)  ((__attribute__((address_space(3))) void*)(p))

__device__ __forceinline__ void gld16(const bf16* gsrc, bf16* ldst) {
  // async global->LDS, 16 bytes/lane; LDS dest must be wave-uniform base (HW adds lane*16)
  __builtin_amdgcn_global_load_lds(AS1C(gsrc), AS3(ldst), 16, 0, 0);
}

// B=2, S=2048, D=1024, H=16, DH=64; M = B*S = 4096

// ---------------- cast x to bf16 ----------------
__global__ void castx_kernel(const float* __restrict__ x, bf16* __restrict__ xb) {
  const int n4 = (4096 * 1024) / 4;
  for (int i = blockIdx.x * blockDim.x + threadIdx.x; i < n4; i += gridDim.x * blockDim.x) {
    float4 v = ((const float4*)x)[i];
    bf16x4 o;
    o[0] = (bf16)v.x; o[1] = (bf16)v.y; o[2] = (bf16)v.z; o[3] = (bf16)v.w;
    ((bf16x4*)xb)[i] = o;
  }
}

// ---------------- prep weights: Wqkv (Q pre-scaled 1/8), Wo2 transpose, scaled biases ----------------
__global__ void prep_kernel(const float* __restrict__ WQ, const float* __restrict__ WK,
                            const float* __restrict__ WV, const float* __restrict__ WO,
                            const float* __restrict__ bQ, const float* __restrict__ bK,
                            const float* __restrict__ bV,
                            bf16* __restrict__ Wqkv, bf16* __restrict__ Wo2,
                            float* __restrict__ biasq) {
  const int WN = 1024 * 1024;
  const int total = 4 * WN + 3072;
  for (int i = blockIdx.x * blockDim.x + threadIdx.x; i < total; i += gridDim.x * blockDim.x) {
    if (i < WN) {
      Wqkv[i] = (bf16)(WQ[i] * 0.125f);          // fold 1/sqrt(DH) into Q
    } else if (i < 2 * WN) {
      Wqkv[i] = (bf16)WK[i - WN];
    } else if (i < 3 * WN) {
      Wqkv[i] = (bf16)WV[i - 2 * WN];
    } else if (i < 4 * WN) {
      int j = i - 3 * WN;                         // W_O flat [H][D][DH]
      int hh = j >> 16, r = j & 65535, d = r >> 6, dh = r & 63;
      Wo2[d * 1024 + hh * 64 + dh] = (bf16)WO[j]; // Wo2[d][h*64+dh]
    } else {
      int n = i - 4 * WN;
      biasq[n] = (n < 1024) ? bQ[n] * 0.125f : (n < 2048) ? bK[n - 1024] : bV[n - 2048];
    }
  }
}

// ---------------- GEMM C[M,N] = A[M,K] * Bw[N,K]^T  (bf16 in, f32 acc) ----------------
// MODE 0: QKV projection -> scatter Q[B,H,S,DH], K[B,H,S,DH], Vt[B,H,DH,S] (bf16, +bias)
// MODE 1: out projection -> Co[M,N] f32 (+bias)
template <int MODE>
__global__ __launch_bounds__(256)
void gemm_bt(const bf16* __restrict__ A, const bf16* __restrict__ Bw,
             const float* __restrict__ bias,
             bf16* __restrict__ Qo, bf16* __restrict__ Ko, bf16* __restrict__ Vt,
             float* __restrict__ Co, int M, int N, int K) {
  __shared__ bf16 As[128 * 64];
  __shared__ bf16 Bs[128 * 64];
  const int tid = threadIdx.x;
  const int lane = tid & 63, w = tid >> 6;
  const int wr = w >> 1, wc = w & 1;
  const int g = lane >> 4, lr = lane & 15;
  const int brow = blockIdx.x * 128, bcol = blockIdx.y * 128;

  f32x4 acc[4][4] = {};

  for (int k0 = 0; k0 < K; k0 += 64) {
#pragma unroll
    for (int it = 0; it < 4; ++it) {
      const int chunk = it * 4 + w;          // wave-uniform
      const int e = chunk * 64 + lane;       // 16B chunk id in tile
      const int row = e >> 3;
      const int c8 = (e & 7) << 3;
      gld16(A + (size_t)(brow + row) * K + k0 + c8, As + chunk * 512);
      gld16(Bw + (size_t)(bcol + row) * K + k0 + c8, Bs + chunk * 512);
    }
    __syncthreads();                          // drains vmcnt: tiles ready
#pragma unroll
    for (int kk = 0; kk < 2; ++kk) {
      bf16x8 af[4], bfm[4];
#pragma unroll
      for (int m = 0; m < 4; ++m)
        af[m] = *(const bf16x8*)(As + (wr * 64 + m * 16 + lr) * 64 + kk * 32 + g * 8);
#pragma unroll
      for (int n = 0; n < 4; ++n)
        bfm[n] = *(const bf16x8*)(Bs + (wc * 64 + n * 16 + lr) * 64 + kk * 32 + g * 8);
#pragma unroll
      for (int m = 0; m < 4; ++m)
#pragma unroll
        for (int n = 0; n < 4; ++n)
          acc[m][n] = __builtin_amdgcn_mfma_f32_16x16x32_bf16(af[m], bfm[n], acc[m][n], 0, 0, 0);
    }
    __syncthreads();                          // protect LDS before next stage
  }

  const int row0 = brow + wr * 64;
  const int col0 = bcol + wc * 64;
#pragma unroll
  for (int m = 0; m < 4; ++m) {
#pragma unroll
    for (int n = 0; n < 4; ++n) {
      const int nidx = col0 + n * 16 + lr;
      f32x4 v = acc[m][n];
      const float bs = bias[nidx];
      if (MODE == 0) {
        const int stream = nidx >> 10;        // 0=Q 1=K 2=V (uniform per 16-lane group)
        const int j = nidx & 1023;
        const int hh = j >> 6, dh = j & 63;
        const int r0 = row0 + m * 16 + g * 4; // token row base; i = 0..3 consecutive
        const int b = r0 >> 11;
        const int p0 = r0 & 2047;
        if (stream == 2) {
          bf16x4 vv;
#pragma unroll
          for (int i = 0; i < 4; ++i) vv[i] = (bf16)(v[i] + bs);
          *(bf16x4*)(Vt + ((size_t)(b * 16 + hh) * 64 + dh) * 2048 + p0) = vv;
        } else {
          bf16* dst = (stream == 0) ? Qo : Ko;
#pragma unroll
          for (int i = 0; i < 4; ++i)
            dst[((size_t)(b * 16 + hh) * 2048 + (p0 + i)) * 64 + dh] = (bf16)(v[i] + bs);
        }
      } else {
#pragma unroll
        for (int i = 0; i < 4; ++i) {
          const int r = row0 + m * 16 + g * 4 + i;
          Co[(size_t)r * 1024 + nidx] = v[i] + bs;
        }
      }
    }
  }
}

// ---------------- causal flash attention (v3: swapped-operand, in-register softmax) ----
// grid: 1024 flat, XCD-bijective decode (all 32 q-tiles of one (b,h) land on one XCD).
// block 256 = 4 waves, wave w owns q-rows [qt*64+16w, +16). Swapped QK^T: s = mfma(K,Q)
// puts a full 64-key slice for q=(lane&15) across the 4 g-lanes -> softmax is in-lane
// trees + 2 shfl_xor. P redistributed to PV B-frag layout via 2-stage register butterfly
// (no LDS). PV swapped too: oacc = mfma(V^T, P^T) -> O^T[dh][q], rescale lane-local.
// K/V LDS-staged (global_load_lds, involution-swizzled source), double-buffered.
__global__ __launch_bounds__(256, 4)
void attn_kernel(const bf16* __restrict__ Qm, const bf16* __restrict__ Km,
                 const bf16* __restrict__ Vm, bf16* __restrict__ Z) {
  const int nblk = blockIdx.x;
  const int xcd = nblk & 7, slot = nblk >> 3;
  const int G = ((slot >> 5) << 3) + xcd;    // (b,h) group 0..31
  const int qt = slot & 31;
  const int hh = G & 15, b = G >> 4;
  const int bh = b * 16 + hh;
  const int lane = threadIdx.x & 63, w = threadIdx.x >> 6;
  const int g = lane >> 4, lr = lane & 15;
  const bool g0 = g & 1, g1 = (g >> 1) & 1;

  __shared__ bf16 Ks[2][4096];               // [buf][64 kv][64 dh], swizzled 16B chunks
  __shared__ bf16 Vs[2][4096];               // [buf][64 dh][64 kv], swizzled 16B chunks

  const bf16* Qb = Qm + (size_t)bh * 2048 * 64;
  const bf16* Kb = Km + (size_t)bh * 2048 * 64;
  const bf16* Vb = Vm + (size_t)bh * 64 * 2048;

  // linear LDS dest + involution-swizzled global source; read side applies same involution
  auto stage = [&](int kv0, int bufi) {
#pragma unroll
    for (int it = 0; it < 2; ++it) {
      const int cb = w * 128 + it * 64;      // wave-uniform chunk base
      const int u = cb + lane;
      const int lc = u ^ ((u >> 3) & 7);
      const int row = lc >> 3, c8 = (lc & 7) * 8;
      gld16(Kb + (size_t)(kv0 + row) * 64 + c8, &Ks[bufi][cb * 8]);
      gld16(Vb + (size_t)row * 2048 + kv0 + c8, &Vs[bufi][cb * 8]);
    }
  };

  const int q0w = qt * 64 + w * 16;
  const int qg = q0w + lr;                   // this lane's q row (swapped layout: col=q=lr)

  bf16x8 aq[2];                              // Q[q=lr][k-slice g] — serves as B-fragment
#pragma unroll
  for (int kk = 0; kk < 2; ++kk)
    aq[kk] = *(const bf16x8*)(Qb + (size_t)qg * 64 + kk * 32 + g * 8);

  float m_i = -1e30f, l_i = 0.f;
  f32x4 oacc[4] = {};                        // oacc[n]: O^T rows dh = n*16+4g+i, col q=lr

  stage(0, 0);
  __syncthreads();
  int buf = 0;

  for (int t = 0; t <= qt; ++t) {
    if (t < qt) stage((t + 1) * 64, buf ^ 1);     // prefetch next tile
    const int kv0 = t * 64;

    // QK^T swapped: s[n] rows = keys n*16+4g+i, col = q = lr
    f32x4 s[4] = {};
#pragma unroll
    for (int kk = 0; kk < 2; ++kk) {
#pragma unroll
      for (int n = 0; n < 4; ++n) {
        const int r = n * 16 + lr;
        const int sl = (r * 8 + kk * 4 + g) ^ (r & 7);
        bf16x8 bk = *(const bf16x8*)(&Ks[buf][sl * 8]);
        s[n] = __builtin_amdgcn_mfma_f32_16x16x32_bf16(bk, aq[kk], s[n], 0, 0, 0);
      }
    }
    if (t == qt) {                           // causal mask on diagonal tile
#pragma unroll
      for (int n = 0; n < 4; ++n)
#pragma unroll
        for (int i = 0; i < 4; ++i)
          if (kv0 + n * 16 + g * 4 + i > qg) s[n][i] = -1e9f;
    }

    // in-lane softmax for q = lr (16 keys/lane, cross-g via 2 shfl)
    float tm = fmaxf(fmaxf(fmaxf(s[0][0], s[0][1]), fmaxf(s[0][2], s[0][3])),
                     fmaxf(fmaxf(s[1][0], s[1][1]), fmaxf(s[1][2], s[1][3])));
    tm = fmaxf(tm, fmaxf(fmaxf(fmaxf(s[2][0], s[2][1]), fmaxf(s[2][2], s[2][3])),
                         fmaxf(fmaxf(s[3][0], s[3][1]), fmaxf(s[3][2], s[3][3]))));
    tm = fmaxf(tm, __shfl_xor(tm, 16));
    tm = fmaxf(tm, __shfl_xor(tm, 32));
    const float mn = fmaxf(m_i, tm);
    const float al = __expf(m_i - mn);
    m_i = mn;
#pragma unroll
    for (int n = 0; n < 4; ++n)
#pragma unroll
      for (int i = 0; i < 4; ++i) s[n][i] = __expf(s[n][i] - mn);
    float ts = ((s[0][0] + s[0][1]) + (s[0][2] + s[0][3])) +
               ((s[1][0] + s[1][1]) + (s[1][2] + s[1][3])) +
               ((s[2][0] + s[2][1]) + (s[2][2] + s[2][3])) +
               ((s[3][0] + s[3][1]) + (s[3][2] + s[3][3]));
    ts += __shfl_xor(ts, 16);
    ts += __shfl_xor(ts, 32);
    l_i = l_i * al + ts;
#pragma unroll
    for (int n = 0; n < 4; ++n)
#pragma unroll
      for (int i = 0; i < 4; ++i) oacc[n][i] *= al;

    // pack P to bf16 pairs: U[n*2+h] = keys {16n+4g+2h, +1} (key-pair c = 8n+2g+h)
    unsigned U[8];
#pragma unroll
    for (int n = 0; n < 4; ++n)
#pragma unroll
      for (int h = 0; h < 2; ++h) {
        unsigned lo = (unsigned)__builtin_bit_cast(unsigned short, (bf16)s[n][2 * h]);
        unsigned hi = (unsigned)__builtin_bit_cast(unsigned short, (bf16)s[n][2 * h + 1]);
        U[n * 2 + h] = lo | (hi << 16);
      }
    // butterfly stage A (xor 32, toggles g1): send slots with n&1 == !g1
    unsigned rA0 = (unsigned)__shfl_xor((int)(g1 ? U[0] : U[2]), 32);
    unsigned rA1 = (unsigned)__shfl_xor((int)(g1 ? U[1] : U[3]), 32);
    unsigned rA2 = (unsigned)__shfl_xor((int)(g1 ? U[4] : U[6]), 32);
    unsigned rA3 = (unsigned)__shfl_xor((int)(g1 ? U[5] : U[7]), 32);
    // V2[c4][c2][c0]: c2==g1 -> kept U[(2*c4+g1)*2+c0]; else received rA[2*c4+c0]
    unsigned v2_000 = g1 ? rA0 : U[0];
    unsigned v2_001 = g1 ? rA1 : U[1];
    unsigned v2_010 = g1 ? U[2] : rA0;
    unsigned v2_011 = g1 ? U[3] : rA1;
    unsigned v2_100 = g1 ? rA2 : U[4];
    unsigned v2_101 = g1 ? rA3 : U[5];
    unsigned v2_110 = g1 ? U[6] : rA2;
    unsigned v2_111 = g1 ? U[7] : rA3;
    // butterfly stage B (xor 16, toggles g0): send c2 == !g0
    unsigned rB0 = (unsigned)__shfl_xor((int)(g0 ? v2_000 : v2_010), 16);
    unsigned rB1 = (unsigned)__shfl_xor((int)(g0 ? v2_001 : v2_011), 16);
    unsigned rB2 = (unsigned)__shfl_xor((int)(g0 ? v2_100 : v2_110), 16);
    unsigned rB3 = (unsigned)__shfl_xor((int)(g0 ? v2_101 : v2_111), 16);
    // T[kk][m] = keys {32kk+8g+2m, +1}: m<2 -> kept-if-!g0, m>=2 -> kept-if-g0
    u32x4 t0, t1;
    t0[0] = g0 ? rB0 : v2_000;
    t0[1] = g0 ? rB1 : v2_001;
    t0[2] = g0 ? v2_010 : rB0;
    t0[3] = g0 ? v2_011 : rB1;
    t1[0] = g0 ? rB2 : v2_100;
    t1[1] = g0 ? rB3 : v2_101;
    t1[2] = g0 ? v2_110 : rB2;
    t1[3] = g0 ? v2_111 : rB3;
    bf16x8 pb0 = __builtin_bit_cast(bf16x8, t0);   // B-frag P^T, kv-slice kk=0
    bf16x8 pb1 = __builtin_bit_cast(bf16x8, t1);   // kk=1

    // PV swapped: oacc[n] += V^T-frag(dh rows n*16+lr) * P^T-frag
#pragma unroll
    for (int kk = 0; kk < 2; ++kk) {
      const bf16x8 pb = kk ? pb1 : pb0;
#pragma unroll
      for (int n = 0; n < 4; ++n) {
        const int r = n * 16 + lr;
        const int sl = (r * 8 + kk * 4 + g) ^ (r & 7);
        bf16x8 av = *(const bf16x8*)(&Vs[buf][sl * 8]);
        oacc[n] = __builtin_amdgcn_mfma_f32_16x16x32_bf16(av, pb, oacc[n], 0, 0, 0);
      }
    }
    __syncthreads();                         // prefetch landed + LDS safe to overwrite
    buf ^= 1;
  }

  const float li = 1.f / l_i;
  bf16* zrow = Z + ((size_t)(b * 2048 + qg) * 16 + hh) * 64;
#pragma unroll
  for (int n = 0; n < 4; ++n) {
    bf16x4 o4;
#pragma unroll
    for (int i = 0; i < 4; ++i) o4[i] = (bf16)(oacc[n][i] * li);
    *(bf16x4*)(zrow + n * 16 + g * 4) = o4;  // dh = n*16 + 4g + i
  }
}

// ---------------- launcher ----------------
extern "C" void kernel_launch(void* const* d_in, const int* in_sizes, int n_in,
                              void* d_out, int out_size, void* d_ws, size_t ws_size,
                              hipStream_t stream) {
  const float* x  = (const float*)d_in[0];
  const float* WQ = (const float*)d_in[1];
  const float* WK = (const float*)d_in[2];
  const float* WV = (const float*)d_in[3];
  const float* WO = (const float*)d_in[4];
  const float* bQ = (const float*)d_in[5];
  const float* bK = (const float*)d_in[6];
  const float* bV = (const float*)d_in[7];
  const float* bO = (const float*)d_in[8];
  float* out = (float*)d_out;

  char* ws = (char*)d_ws;
  bf16* xb    = (bf16*)(ws);                        // 8 MB  [4096,1024]
  bf16* Wqkv  = (bf16*)(ws + (8u << 20));           // 6 MB  [3072,1024]
  bf16* Wo2   = (bf16*)(ws + (14u << 20));          // 2 MB  [1024,1024]
  bf16* Qb    = (bf16*)(ws + (16u << 20));          // 8 MB  [B,H,S,DH]
  bf16* Kb    = (bf16*)(ws + (24u << 20));          // 8 MB  [B,H,S,DH]
  bf16* Vtb   = (bf16*)(ws + (32u << 20));          // 8 MB  [B,H,DH,S]
  bf16* Zb    = (bf16*)(ws + (40u << 20));          // 8 MB  [4096,1024]
  float* biasq = (float*)(ws + (48u << 20));        // 12 KB [3072]

  castx_kernel<<<2048, 256, 0, stream>>>(x, xb);
  prep_kernel<<<2048, 256, 0, stream>>>(WQ, WK, WV, WO, bQ, bK, bV, Wqkv, Wo2, biasq);
  gemm_bt<0><<<dim3(32, 24), 256, 0, stream>>>(xb, Wqkv, biasq, Qb, Kb, Vtb, nullptr,
                                               4096, 3072, 1024);
  attn_kernel<<<1024, 256, 0, stream>>>(Qb, Kb, Vtb, Zb);
  gemm_bt<1><<<dim3(32, 8), 256, 0, stream>>>(Zb, Wo2, bO, nullptr, nullptr, nullptr, out,
                                              4096, 1024, 1024);
}

// Round 6
// 222.931 us; speedup vs baseline: 1.0939x; 1.0939x over previous
//
#include <hip/hip_runtime.h>

// ---------------- types ----------------
typedef __bf16 bf16;
typedef __bf16 bf16x4 __attribute__((ext_vector_type(4)));
typedef __bf16 bf16x8 __attribute__((ext_vector_type(8)));
typedef float f32x4 __attribute__((ext_vector_type(4)));
typedef unsigned u32x4 __attribute__((ext_vector_type(4)));

#define AS1C(p) ((const __attribute__((address_space(1))) void*)(p))
#define AS3(p)  ((__attribute__((address_space(3))) void*)(p))

__device__ __forceinline__ void gld16(const bf16* gsrc, bf16* ldst) {
  // async global->LDS, 16 bytes/lane; LDS dest must be wave-uniform base (HW adds lane*16)
  __builtin_amdgcn_global_load_lds(AS1C(gsrc), AS3(ldst), 16, 0, 0);
}

// B=2, S=2048, D=1024, H=16, DH=64; M = B*S = 4096

// ---------------- cast x to bf16 ----------------
__global__ void castx_kernel(const float* __restrict__ x, bf16* __restrict__ xb) {
  const int n4 = (4096 * 1024) / 4;
  for (int i = blockIdx.x * blockDim.x + threadIdx.x; i < n4; i += gridDim.x * blockDim.x) {
    float4 v = ((const float4*)x)[i];
    bf16x4 o;
    o[0] = (bf16)v.x; o[1] = (bf16)v.y; o[2] = (bf16)v.z; o[3] = (bf16)v.w;
    ((bf16x4*)xb)[i] = o;
  }
}

// ---------------- prep weights: Wqkv (Q pre-scaled 1/8), Wo2 transpose, scaled biases ----------------
__global__ void prep_kernel(const float* __restrict__ WQ, const float* __restrict__ WK,
                            const float* __restrict__ WV, const float* __restrict__ WO,
                            const float* __restrict__ bQ, const float* __restrict__ bK,
                            const float* __restrict__ bV,
                            bf16* __restrict__ Wqkv, bf16* __restrict__ Wo2,
                            float* __restrict__ biasq) {
  const int WN = 1024 * 1024;
  const int total = 4 * WN + 3072;
  for (int i = blockIdx.x * blockDim.x + threadIdx.x; i < total; i += gridDim.x * blockDim.x) {
    if (i < WN) {
      Wqkv[i] = (bf16)(WQ[i] * 0.125f);          // fold 1/sqrt(DH) into Q
    } else if (i < 2 * WN) {
      Wqkv[i] = (bf16)WK[i - WN];
    } else if (i < 3 * WN) {
      Wqkv[i] = (bf16)WV[i - 2 * WN];
    } else if (i < 4 * WN) {
      int j = i - 3 * WN;                         // W_O flat [H][D][DH]
      int hh = j >> 16, r = j & 65535, d = r >> 6, dh = r & 63;
      Wo2[d * 1024 + hh * 64 + dh] = (bf16)WO[j]; // Wo2[d][h*64+dh]
    } else {
      int n = i - 4 * WN;
      biasq[n] = (n < 1024) ? bQ[n] * 0.125f : (n < 2048) ? bK[n - 1024] : bV[n - 2048];
    }
  }
}

// ---------------- GEMM C[M,N] = A[M,K] * Bw[N,K]^T  (bf16 in, f32 acc) ----------------
// MODE 0: QKV projection -> scatter Q[B,H,S,DH], K[B,H,S,DH], Vt[B,H,DH,S] (bf16, +bias)
// MODE 1: out projection -> Co[M,N] f32 (+bias)
template <int MODE>
__global__ __launch_bounds__(256)
void gemm_bt(const bf16* __restrict__ A, const bf16* __restrict__ Bw,
             const float* __restrict__ bias,
             bf16* __restrict__ Qo, bf16* __restrict__ Ko, bf16* __restrict__ Vt,
             float* __restrict__ Co, int M, int N, int K) {
  __shared__ bf16 As[128 * 64];
  __shared__ bf16 Bs[128 * 64];
  const int tid = threadIdx.x;
  const int lane = tid & 63, w = tid >> 6;
  const int wr = w >> 1, wc = w & 1;
  const int g = lane >> 4, lr = lane & 15;
  const int brow = blockIdx.x * 128, bcol = blockIdx.y * 128;

  f32x4 acc[4][4] = {};

  for (int k0 = 0; k0 < K; k0 += 64) {
#pragma unroll
    for (int it = 0; it < 4; ++it) {
      const int chunk = it * 4 + w;          // wave-uniform
      const int e = chunk * 64 + lane;       // 16B chunk id in tile
      const int row = e >> 3;
      const int c8 = (e & 7) << 3;
      gld16(A + (size_t)(brow + row) * K + k0 + c8, As + chunk * 512);
      gld16(Bw + (size_t)(bcol + row) * K + k0 + c8, Bs + chunk * 512);
    }
    __syncthreads();                          // drains vmcnt: tiles ready
#pragma unroll
    for (int kk = 0; kk < 2; ++kk) {
      bf16x8 af[4], bfm[4];
#pragma unroll
      for (int m = 0; m < 4; ++m)
        af[m] = *(const bf16x8*)(As + (wr * 64 + m * 16 + lr) * 64 + kk * 32 + g * 8);
#pragma unroll
      for (int n = 0; n < 4; ++n)
        bfm[n] = *(const bf16x8*)(Bs + (wc * 64 + n * 16 + lr) * 64 + kk * 32 + g * 8);
#pragma unroll
      for (int m = 0; m < 4; ++m)
#pragma unroll
        for (int n = 0; n < 4; ++n)
          acc[m][n] = __builtin_amdgcn_mfma_f32_16x16x32_bf16(af[m], bfm[n], acc[m][n], 0, 0, 0);
    }
    __syncthreads();                          // protect LDS before next stage
  }

  const int row0 = brow + wr * 64;
  const int col0 = bcol + wc * 64;
#pragma unroll
  for (int m = 0; m < 4; ++m) {
#pragma unroll
    for (int n = 0; n < 4; ++n) {
      const int nidx = col0 + n * 16 + lr;
      f32x4 v = acc[m][n];
      const float bs = bias[nidx];
      if (MODE == 0) {
        const int stream = nidx >> 10;        // 0=Q 1=K 2=V (uniform per 16-lane group)
        const int j = nidx & 1023;
        const int hh = j >> 6, dh = j & 63;
        const int r0 = row0 + m * 16 + g * 4; // token row base; i = 0..3 consecutive
        const int b = r0 >> 11;
        const int p0 = r0 & 2047;
        if (stream == 2) {
          bf16x4 vv;
#pragma unroll
          for (int i = 0; i < 4; ++i) vv[i] = (bf16)(v[i] + bs);
          *(bf16x4*)(Vt + ((size_t)(b * 16 + hh) * 64 + dh) * 2048 + p0) = vv;
        } else {
          bf16* dst = (stream == 0) ? Qo : Ko;
#pragma unroll
          for (int i = 0; i < 4; ++i)
            dst[((size_t)(b * 16 + hh) * 2048 + (p0 + i)) * 64 + dh] = (bf16)(v[i] + bs);
        }
      } else {
#pragma unroll
        for (int i = 0; i < 4; ++i) {
          const int r = row0 + m * 16 + g * 4 + i;
          Co[(size_t)r * 1024 + nidx] = v[i] + bs;
        }
      }
    }
  }
}

// ---------------- causal flash attention (v4: swapped-operand + balanced q-tile pairs) --
// grid: 512 flat. Decode: xcd = blk&7, slot = blk>>3; G = (slot>>4)*8 + xcd (b,h group,
// all 16 pairs of one (b,h) on one XCD); qp = slot&15. Block runs q-tiles {qp, 31-qp}
// sequentially -> every block exactly 33 KV-tile iterations (load-balanced makespan).
// Per q-tile: swapped QK^T (s = mfma(K,Q)) -> in-lane softmax (2 shfl) -> register
// butterfly P-redistribution -> swapped PV (oacc = mfma(V^T,P^T)). No P LDS, 0 bank
// conflicts. K/V LDS-staged (global_load_lds, involution-swizzled source), dbuf.
__global__ __launch_bounds__(256, 4)
void attn_kernel(const bf16* __restrict__ Qm, const bf16* __restrict__ Km,
                 const bf16* __restrict__ Vm, bf16* __restrict__ Z) {
  const int nblk = blockIdx.x;
  const int xcd = nblk & 7, slot = nblk >> 3;
  const int G = ((slot >> 4) << 3) + xcd;    // (b,h) group 0..31
  const int qp = slot & 15;                  // pair index
  const int hh = G & 15, b = G >> 4;
  const int bh = b * 16 + hh;
  const int lane = threadIdx.x & 63, w = threadIdx.x >> 6;
  const int g = lane >> 4, lr = lane & 15;
  const bool g0 = g & 1, g1 = (g >> 1) & 1;

  __shared__ bf16 Ks[2][4096];               // [buf][64 kv][64 dh], swizzled 16B chunks
  __shared__ bf16 Vs[2][4096];               // [buf][64 dh][64 kv], swizzled 16B chunks

  const bf16* Qb = Qm + (size_t)bh * 2048 * 64;
  const bf16* Kb = Km + (size_t)bh * 2048 * 64;
  const bf16* Vb = Vm + (size_t)bh * 64 * 2048;

  // linear LDS dest + involution-swizzled global source; read side applies same involution
  auto stage = [&](int kv0, int bufi) {
#pragma unroll
    for (int it = 0; it < 2; ++it) {
      const int cb = w * 128 + it * 64;      // wave-uniform chunk base
      const int u = cb + lane;
      const int lc = u ^ ((u >> 3) & 7);
      const int row = lc >> 3, c8 = (lc & 7) * 8;
      gld16(Kb + (size_t)(kv0 + row) * 64 + c8, &Ks[bufi][cb * 8]);
      gld16(Vb + (size_t)row * 2048 + kv0 + c8, &Vs[bufi][cb * 8]);
    }
  };

  int buf = 0;
  for (int half = 0; half < 2; ++half) {
    const int qt = half ? 31 - qp : qp;
    const int q0w = qt * 64 + w * 16;
    const int qg = q0w + lr;                 // this lane's q row (swapped layout: col=q=lr)

    bf16x8 aq[2];                            // Q[q=lr][k-slice g] — serves as B-fragment
#pragma unroll
    for (int kk = 0; kk < 2; ++kk)
      aq[kk] = *(const bf16x8*)(Qb + (size_t)qg * 64 + kk * 32 + g * 8);

    float m_i = -1e30f, l_i = 0.f;
    f32x4 oacc[4] = {};                      // oacc[n]: O^T rows dh = n*16+4g+i, col q=lr

    stage(0, buf);
    __syncthreads();

    for (int t = 0; t <= qt; ++t) {
      if (t < qt) stage((t + 1) * 64, buf ^ 1);   // prefetch next tile
      const int kv0 = t * 64;

      // QK^T swapped: s[n] rows = keys n*16+4g+i, col = q = lr
      f32x4 s[4] = {};
#pragma unroll
      for (int kk = 0; kk < 2; ++kk) {
#pragma unroll
        for (int n = 0; n < 4; ++n) {
          const int r = n * 16 + lr;
          const int sl = (r * 8 + kk * 4 + g) ^ (r & 7);
          bf16x8 bk = *(const bf16x8*)(&Ks[buf][sl * 8]);
          s[n] = __builtin_amdgcn_mfma_f32_16x16x32_bf16(bk, aq[kk], s[n], 0, 0, 0);
        }
      }
      if (t == qt) {                         // causal mask on diagonal tile
#pragma unroll
        for (int n = 0; n < 4; ++n)
#pragma unroll
          for (int i = 0; i < 4; ++i)
            if (kv0 + n * 16 + g * 4 + i > qg) s[n][i] = -1e9f;
      }

      // in-lane softmax for q = lr (16 keys/lane, cross-g via 2 shfl)
      float tm = fmaxf(fmaxf(fmaxf(s[0][0], s[0][1]), fmaxf(s[0][2], s[0][3])),
                       fmaxf(fmaxf(s[1][0], s[1][1]), fmaxf(s[1][2], s[1][3])));
      tm = fmaxf(tm, fmaxf(fmaxf(fmaxf(s[2][0], s[2][1]), fmaxf(s[2][2], s[2][3])),
                           fmaxf(fmaxf(s[3][0], s[3][1]), fmaxf(s[3][2], s[3][3]))));
      tm = fmaxf(tm, __shfl_xor(tm, 16));
      tm = fmaxf(tm, __shfl_xor(tm, 32));
      const float mn = fmaxf(m_i, tm);
      const float al = __expf(m_i - mn);
      m_i = mn;
#pragma unroll
      for (int n = 0; n < 4; ++n)
#pragma unroll
        for (int i = 0; i < 4; ++i) s[n][i] = __expf(s[n][i] - mn);
      float ts = ((s[0][0] + s[0][1]) + (s[0][2] + s[0][3])) +
                 ((s[1][0] + s[1][1]) + (s[1][2] + s[1][3])) +
                 ((s[2][0] + s[2][1]) + (s[2][2] + s[2][3])) +
                 ((s[3][0] + s[3][1]) + (s[3][2] + s[3][3]));
      ts += __shfl_xor(ts, 16);
      ts += __shfl_xor(ts, 32);
      l_i = l_i * al + ts;
#pragma unroll
      for (int n = 0; n < 4; ++n)
#pragma unroll
        for (int i = 0; i < 4; ++i) oacc[n][i] *= al;

      // pack P to bf16 pairs: U[n*2+h] = keys {16n+4g+2h, +1} (key-pair c = 8n+2g+h)
      unsigned U[8];
#pragma unroll
      for (int n = 0; n < 4; ++n)
#pragma unroll
        for (int h = 0; h < 2; ++h) {
          unsigned lo = (unsigned)__builtin_bit_cast(unsigned short, (bf16)s[n][2 * h]);
          unsigned hi = (unsigned)__builtin_bit_cast(unsigned short, (bf16)s[n][2 * h + 1]);
          U[n * 2 + h] = lo | (hi << 16);
        }
      // butterfly stage A (xor 32, toggles g1): send slots with n&1 == !g1
      unsigned rA0 = (unsigned)__shfl_xor((int)(g1 ? U[0] : U[2]), 32);
      unsigned rA1 = (unsigned)__shfl_xor((int)(g1 ? U[1] : U[3]), 32);
      unsigned rA2 = (unsigned)__shfl_xor((int)(g1 ? U[4] : U[6]), 32);
      unsigned rA3 = (unsigned)__shfl_xor((int)(g1 ? U[5] : U[7]), 32);
      // V2[c4][c2][c0]: c2==g1 -> kept U[(2*c4+g1)*2+c0]; else received rA[2*c4+c0]
      unsigned v2_000 = g1 ? rA0 : U[0];
      unsigned v2_001 = g1 ? rA1 : U[1];
      unsigned v2_010 = g1 ? U[2] : rA0;
      unsigned v2_011 = g1 ? U[3] : rA1;
      unsigned v2_100 = g1 ? rA2 : U[4];
      unsigned v2_101 = g1 ? rA3 : U[5];
      unsigned v2_110 = g1 ? U[6] : rA2;
      unsigned v2_111 = g1 ? U[7] : rA3;
      // butterfly stage B (xor 16, toggles g0): send c2 == !g0
      unsigned rB0 = (unsigned)__shfl_xor((int)(g0 ? v2_000 : v2_010), 16);
      unsigned rB1 = (unsigned)__shfl_xor((int)(g0 ? v2_001 : v2_011), 16);
      unsigned rB2 = (unsigned)__shfl_xor((int)(g0 ? v2_100 : v2_110), 16);
      unsigned rB3 = (unsigned)__shfl_xor((int)(g0 ? v2_101 : v2_111), 16);
      // T[kk][m] = keys {32kk+8g+2m, +1}: m<2 -> kept-if-!g0, m>=2 -> kept-if-g0
      u32x4 t0, t1;
      t0[0] = g0 ? rB0 : v2_000;
      t0[1] = g0 ? rB1 : v2_001;
      t0[2] = g0 ? v2_010 : rB0;
      t0[3] = g0 ? v2_011 : rB1;
      t1[0] = g0 ? rB2 : v2_100;
      t1[1] = g0 ? rB3 : v2_101;
      t1[2] = g0 ? v2_110 : rB2;
      t1[3] = g0 ? v2_111 : rB3;
      bf16x8 pb0 = __builtin_bit_cast(bf16x8, t0); // B-frag P^T, kv-slice kk=0
      bf16x8 pb1 = __builtin_bit_cast(bf16x8, t1); // kk=1

      // PV swapped: oacc[n] += V^T-frag(dh rows n*16+lr) * P^T-frag
#pragma unroll
      for (int kk = 0; kk < 2; ++kk) {
        const bf16x8 pb = kk ? pb1 : pb0;
#pragma unroll
        for (int n = 0; n < 4; ++n) {
          const int r = n * 16 + lr;
          const int sl = (r * 8 + kk * 4 + g) ^ (r & 7);
          bf16x8 av = *(const bf16x8*)(&Vs[buf][sl * 8]);
          oacc[n] = __builtin_amdgcn_mfma_f32_16x16x32_bf16(av, pb, oacc[n], 0, 0, 0);
        }
      }
      __syncthreads();                       // prefetch landed + LDS safe to overwrite
      buf ^= 1;
    }

    const float li = 1.f / l_i;
    bf16* zrow = Z + ((size_t)(b * 2048 + qg) * 16 + hh) * 64;
#pragma unroll
    for (int n = 0; n < 4; ++n) {
      bf16x4 o4;
#pragma unroll
      for (int i = 0; i < 4; ++i) o4[i] = (bf16)(oacc[n][i] * li);
      *(bf16x4*)(zrow + n * 16 + g * 4) = o4; // dh = n*16 + 4g + i
    }
  }
}

// ---------------- launcher ----------------
extern "C" void kernel_launch(void* const* d_in, const int* in_sizes, int n_in,
                              void* d_out, int out_size, void* d_ws, size_t ws_size,
                              hipStream_t stream) {
  const float* x  = (const float*)d_in[0];
  const float* WQ = (const float*)d_in[1];
  const float* WK = (const float*)d_in[2];
  const float* WV = (const float*)d_in[3];
  const float* WO = (const float*)d_in[4];
  const float* bQ = (const float*)d_in[5];
  const float* bK = (const float*)d_in[6];
  const float* bV = (const float*)d_in[7];
  const float* bO = (const float*)d_in[8];
  float* out = (float*)d_out;

  char* ws = (char*)d_ws;
  bf16* xb    = (bf16*)(ws);                        // 8 MB  [4096,1024]
  bf16* Wqkv  = (bf16*)(ws + (8u << 20));           // 6 MB  [3072,1024]
  bf16* Wo2   = (bf16*)(ws + (14u << 20));          // 2 MB  [1024,1024]
  bf16* Qb    = (bf16*)(ws + (16u << 20));          // 8 MB  [B,H,S,DH]
  bf16* Kb    = (bf16*)(ws + (24u << 20));          // 8 MB  [B,H,S,DH]
  bf16* Vtb   = (bf16*)(ws + (32u << 20));          // 8 MB  [B,H,DH,S]
  bf16* Zb    = (bf16*)(ws + (40u << 20));          // 8 MB  [4096,1024]
  float* biasq = (float*)(ws + (48u << 20));        // 12 KB [3072]

  castx_kernel<<<2048, 256, 0, stream>>>(x, xb);
  prep_kernel<<<2048, 256, 0, stream>>>(WQ, WK, WV, WO, bQ, bK, bV, Wqkv, Wo2, biasq);
  gemm_bt<0><<<dim3(32, 24), 256, 0, stream>>>(xb, Wqkv, biasq, Qb, Kb, Vtb, nullptr,
                                               4096, 3072, 1024);
  attn_kernel<<<512, 256, 0, stream>>>(Qb, Kb, Vtb, Zb);
  gemm_bt<1><<<dim3(32, 8), 256, 0, stream>>>(Zb, Wo2, bO, nullptr, nullptr, nullptr, out,
                                              4096, 1024, 1024);
}

// Round 7
// 221.521 us; speedup vs baseline: 1.1009x; 1.0064x over previous
//
#include <hip/hip_runtime.h>

// ---------------- types ----------------
typedef __bf16 bf16;
typedef __bf16 bf16x4 __attribute__((ext_vector_type(4)));
typedef __bf16 bf16x8 __attribute__((ext_vector_type(8)));
typedef float f32x4 __attribute__((ext_vector_type(4)));
typedef unsigned u32x4 __attribute__((ext_vector_type(4)));

#define AS1C(p) ((const __attribute__((address_space(1))) void*)(p))
#define AS3(p)  ((__attribute__((address_space(3))) void*)(p))

__device__ __forceinline__ void gld16(const bf16* gsrc, bf16* ldst) {
  // async global->LDS, 16 bytes/lane; LDS dest must be wave-uniform base (HW adds lane*16)
  __builtin_amdgcn_global_load_lds(AS1C(gsrc), AS3(ldst), 16, 0, 0);
}

// B=2, S=2048, D=1024, H=16, DH=64; M = B*S = 4096

// ---------------- cast x to bf16 ----------------
__global__ void castx_kernel(const float* __restrict__ x, bf16* __restrict__ xb) {
  const int n4 = (4096 * 1024) / 4;
  for (int i = blockIdx.x * blockDim.x + threadIdx.x; i < n4; i += gridDim.x * blockDim.x) {
    float4 v = ((const float4*)x)[i];
    bf16x4 o;
    o[0] = (bf16)v.x; o[1] = (bf16)v.y; o[2] = (bf16)v.z; o[3] = (bf16)v.w;
    ((bf16x4*)xb)[i] = o;
  }
}

// ---------------- prep weights: Wqkv (Q pre-scaled 1/8), Wo2 transpose, scaled biases ----------------
__global__ void prep_kernel(const float* __restrict__ WQ, const float* __restrict__ WK,
                            const float* __restrict__ WV, const float* __restrict__ WO,
                            const float* __restrict__ bQ, const float* __restrict__ bK,
                            const float* __restrict__ bV,
                            bf16* __restrict__ Wqkv, bf16* __restrict__ Wo2,
                            float* __restrict__ biasq) {
  const int WN = 1024 * 1024;
  const int total = 4 * WN + 3072;
  for (int i = blockIdx.x * blockDim.x + threadIdx.x; i < total; i += gridDim.x * blockDim.x) {
    if (i < WN) {
      Wqkv[i] = (bf16)(WQ[i] * 0.125f);          // fold 1/sqrt(DH) into Q
    } else if (i < 2 * WN) {
      Wqkv[i] = (bf16)WK[i - WN];
    } else if (i < 3 * WN) {
      Wqkv[i] = (bf16)WV[i - 2 * WN];
    } else if (i < 4 * WN) {
      int j = i - 3 * WN;                         // W_O flat [H][D][DH]
      int hh = j >> 16, r = j & 65535, d = r >> 6, dh = r & 63;
      Wo2[d * 1024 + hh * 64 + dh] = (bf16)WO[j]; // Wo2[d][h*64+dh]
    } else {
      int n = i - 4 * WN;
      biasq[n] = (n < 1024) ? bQ[n] * 0.125f : (n < 2048) ? bK[n - 1024] : bV[n - 2048];
    }
  }
}

// ---------------- GEMM C[M,N] = A[M,K] * Bw[N,K]^T  (bf16 in, f32 acc) ----------------
// MODE 0: QKV projection -> scatter Q[B,H,S,DH], K[B,H,S,DH], Vt[B,H,DH,S] (bf16, +bias)
// MODE 1: out projection -> Co[M,N] f32 (+bias)
template <int MODE>
__global__ __launch_bounds__(256)
void gemm_bt(const bf16* __restrict__ A, const bf16* __restrict__ Bw,
             const float* __restrict__ bias,
             bf16* __restrict__ Qo, bf16* __restrict__ Ko, bf16* __restrict__ Vt,
             float* __restrict__ Co, int M, int N, int K) {
  __shared__ bf16 As[128 * 64];
  __shared__ bf16 Bs[128 * 64];
  const int tid = threadIdx.x;
  const int lane = tid & 63, w = tid >> 6;
  const int wr = w >> 1, wc = w & 1;
  const int g = lane >> 4, lr = lane & 15;
  const int brow = blockIdx.x * 128, bcol = blockIdx.y * 128;

  f32x4 acc[4][4] = {};

  for (int k0 = 0; k0 < K; k0 += 64) {
#pragma unroll
    for (int it = 0; it < 4; ++it) {
      const int chunk = it * 4 + w;          // wave-uniform
      const int e = chunk * 64 + lane;       // 16B chunk id in tile
      const int row = e >> 3;
      const int c8 = (e & 7) << 3;
      gld16(A + (size_t)(brow + row) * K + k0 + c8, As + chunk * 512);
      gld16(Bw + (size_t)(bcol + row) * K + k0 + c8, Bs + chunk * 512);
    }
    __syncthreads();                          // drains vmcnt: tiles ready
#pragma unroll
    for (int kk = 0; kk < 2; ++kk) {
      bf16x8 af[4], bfm[4];
#pragma unroll
      for (int m = 0; m < 4; ++m)
        af[m] = *(const bf16x8*)(As + (wr * 64 + m * 16 + lr) * 64 + kk * 32 + g * 8);
#pragma unroll
      for (int n = 0; n < 4; ++n)
        bfm[n] = *(const bf16x8*)(Bs + (wc * 64 + n * 16 + lr) * 64 + kk * 32 + g * 8);
#pragma unroll
      for (int m = 0; m < 4; ++m)
#pragma unroll
        for (int n = 0; n < 4; ++n)
          acc[m][n] = __builtin_amdgcn_mfma_f32_16x16x32_bf16(af[m], bfm[n], acc[m][n], 0, 0, 0);
    }
    __syncthreads();                          // protect LDS before next stage
  }

  const int row0 = brow + wr * 64;
  const int col0 = bcol + wc * 64;
#pragma unroll
  for (int m = 0; m < 4; ++m) {
#pragma unroll
    for (int n = 0; n < 4; ++n) {
      const int nidx = col0 + n * 16 + lr;
      f32x4 v = acc[m][n];
      const float bs = bias[nidx];
      if (MODE == 0) {
        const int stream = nidx >> 10;        // 0=Q 1=K 2=V (uniform per 16-lane group)
        const int j = nidx & 1023;
        const int hh = j >> 6, dh = j & 63;
        const int r0 = row0 + m * 16 + g * 4; // token row base; i = 0..3 consecutive
        const int b = r0 >> 11;
        const int p0 = r0 & 2047;
        if (stream == 2) {
          bf16x4 vv;
#pragma unroll
          for (int i = 0; i < 4; ++i) vv[i] = (bf16)(v[i] + bs);
          *(bf16x4*)(Vt + ((size_t)(b * 16 + hh) * 64 + dh) * 2048 + p0) = vv;
        } else {
          bf16* dst = (stream == 0) ? Qo : Ko;
#pragma unroll
          for (int i = 0; i < 4; ++i)
            dst[((size_t)(b * 16 + hh) * 2048 + (p0 + i)) * 64 + dh] = (bf16)(v[i] + bs);
        }
      } else {
#pragma unroll
        for (int i = 0; i < 4; ++i) {
          const int r = row0 + m * 16 + g * 4 + i;
          Co[(size_t)r * 1024 + nidx] = v[i] + bs;
        }
      }
    }
  }
}

// ---------------- causal flash attention (v5: swapped-operand + selective KV-split) ----
// grid 1536 flat. xcd = blk&7; s2 = blk>>3 (0..191); Gl = s2&3; u = s2>>2 (0..47);
// G = (b,h) = Gl*8 + xcd  (4 groups per XCD, all their blocks XCD-local).
// u<32: SPLIT block for qt = 31-(u>>1), spl = u&1: covers t in [0,mid) or [mid,qt+1),
//       mid = (qt+2)>>1; writes UNNORMALIZED partials OP[spl] (bf16) + ML[spl] (m,l).
// u>=32: UNSPLIT block qt = 47-u (<=15): full range, writes normalized Z directly.
// Long (16-17 iter) blocks dispatch first; every block <= 17 iterations -> balanced w/
// backfill queue (~6 blocks/CU vs LDS cap 5). Per-tile math identical to v4.
__global__ __launch_bounds__(256, 4)
void attn_kernel(const bf16* __restrict__ Qm, const bf16* __restrict__ Km,
                 const bf16* __restrict__ Vm, bf16* __restrict__ Z,
                 bf16* __restrict__ OP, float2* __restrict__ ML) {
  const int nblk = blockIdx.x;
  const int xcd = nblk & 7, s2 = nblk >> 3;
  const int Gl = s2 & 3, u = s2 >> 2;        // u in [0,48)
  const int G = Gl * 8 + xcd;                // (b,h) group 0..31
  const int hh = G & 15, b = G >> 4;
  const int lane = threadIdx.x & 63, w = threadIdx.x >> 6;
  const int g = lane >> 4, lr = lane & 15;
  const bool g0 = g & 1, g1 = (g >> 1) & 1;

  int qt, t0, t1, spl;
  if (u < 32) {
    qt = 31 - (u >> 1); spl = u & 1;
    const int T = qt + 1, mid = (T + 1) >> 1;
    t0 = spl ? mid : 0; t1 = spl ? T : mid;
  } else {
    qt = 47 - u; spl = -1; t0 = 0; t1 = qt + 1;
  }

  __shared__ bf16 Ks[2][4096];               // [buf][64 kv][64 dh], swizzled 16B chunks
  __shared__ bf16 Vs[2][4096];               // [buf][64 dh][64 kv], swizzled 16B chunks

  const bf16* Qb = Qm + (size_t)G * 2048 * 64;
  const bf16* Kb = Km + (size_t)G * 2048 * 64;
  const bf16* Vb = Vm + (size_t)G * 64 * 2048;

  // linear LDS dest + involution-swizzled global source; read side applies same involution
  auto stage = [&](int kv0, int bufi) {
#pragma unroll
    for (int it = 0; it < 2; ++it) {
      const int cb = w * 128 + it * 64;      // wave-uniform chunk base
      const int uu = cb + lane;
      const int lc = uu ^ ((uu >> 3) & 7);
      const int row = lc >> 3, c8 = (lc & 7) * 8;
      gld16(Kb + (size_t)(kv0 + row) * 64 + c8, &Ks[bufi][cb * 8]);
      gld16(Vb + (size_t)row * 2048 + kv0 + c8, &Vs[bufi][cb * 8]);
    }
  };

  const int q0w = qt * 64 + w * 16;
  const int qg = q0w + lr;                   // this lane's q row (swapped layout: col=q=lr)

  bf16x8 aq[2];                              // Q[q=lr][k-slice g] — serves as B-fragment
#pragma unroll
  for (int kk = 0; kk < 2; ++kk)
    aq[kk] = *(const bf16x8*)(Qb + (size_t)qg * 64 + kk * 32 + g * 8);

  float m_i = -1e30f, l_i = 0.f;
  f32x4 oacc[4] = {};                        // oacc[n]: O^T rows dh = n*16+4g+i, col q=lr

  int buf = 0;
  stage(t0 * 64, 0);
  __syncthreads();

  for (int t = t0; t < t1; ++t) {
    if (t + 1 < t1) stage((t + 1) * 64, buf ^ 1);  // prefetch next tile
    const int kv0 = t * 64;

    // QK^T swapped: s[n] rows = keys n*16+4g+i, col = q = lr
    f32x4 s[4] = {};
#pragma unroll
    for (int kk = 0; kk < 2; ++kk) {
#pragma unroll
      for (int n = 0; n < 4; ++n) {
        const int r = n * 16 + lr;
        const int sl = (r * 8 + kk * 4 + g) ^ (r & 7);
        bf16x8 bk = *(const bf16x8*)(&Ks[buf][sl * 8]);
        s[n] = __builtin_amdgcn_mfma_f32_16x16x32_bf16(bk, aq[kk], s[n], 0, 0, 0);
      }
    }
    if (t == qt) {                           // causal mask on diagonal tile
#pragma unroll
      for (int n = 0; n < 4; ++n)
#pragma unroll
        for (int i = 0; i < 4; ++i)
          if (kv0 + n * 16 + g * 4 + i > qg) s[n][i] = -1e9f;
    }

    // in-lane softmax for q = lr (16 keys/lane, cross-g via 2 shfl)
    float tm = fmaxf(fmaxf(fmaxf(s[0][0], s[0][1]), fmaxf(s[0][2], s[0][3])),
                     fmaxf(fmaxf(s[1][0], s[1][1]), fmaxf(s[1][2], s[1][3])));
    tm = fmaxf(tm, fmaxf(fmaxf(fmaxf(s[2][0], s[2][1]), fmaxf(s[2][2], s[2][3])),
                         fmaxf(fmaxf(s[3][0], s[3][1]), fmaxf(s[3][2], s[3][3]))));
    tm = fmaxf(tm, __shfl_xor(tm, 16));
    tm = fmaxf(tm, __shfl_xor(tm, 32));
    const float mn = fmaxf(m_i, tm);
    const float al = __expf(m_i - mn);
    m_i = mn;
#pragma unroll
    for (int n = 0; n < 4; ++n)
#pragma unroll
      for (int i = 0; i < 4; ++i) s[n][i] = __expf(s[n][i] - mn);
    float ts = ((s[0][0] + s[0][1]) + (s[0][2] + s[0][3])) +
               ((s[1][0] + s[1][1]) + (s[1][2] + s[1][3])) +
               ((s[2][0] + s[2][1]) + (s[2][2] + s[2][3])) +
               ((s[3][0] + s[3][1]) + (s[3][2] + s[3][3]));
    ts += __shfl_xor(ts, 16);
    ts += __shfl_xor(ts, 32);
    l_i = l_i * al + ts;
#pragma unroll
    for (int n = 0; n < 4; ++n)
#pragma unroll
      for (int i = 0; i < 4; ++i) oacc[n][i] *= al;

    // pack P to bf16 pairs: U[n*2+h] = keys {16n+4g+2h, +1} (key-pair c = 8n+2g+h)
    unsigned U[8];
#pragma unroll
    for (int n = 0; n < 4; ++n)
#pragma unroll
      for (int h = 0; h < 2; ++h) {
        unsigned lo = (unsigned)__builtin_bit_cast(unsigned short, (bf16)s[n][2 * h]);
        unsigned hi = (unsigned)__builtin_bit_cast(unsigned short, (bf16)s[n][2 * h + 1]);
        U[n * 2 + h] = lo | (hi << 16);
      }
    // butterfly stage A (xor 32, toggles g1): send slots with n&1 == !g1
    unsigned rA0 = (unsigned)__shfl_xor((int)(g1 ? U[0] : U[2]), 32);
    unsigned rA1 = (unsigned)__shfl_xor((int)(g1 ? U[1] : U[3]), 32);
    unsigned rA2 = (unsigned)__shfl_xor((int)(g1 ? U[4] : U[6]), 32);
    unsigned rA3 = (unsigned)__shfl_xor((int)(g1 ? U[5] : U[7]), 32);
    // V2[c4][c2][c0]: c2==g1 -> kept U[(2*c4+g1)*2+c0]; else received rA[2*c4+c0]
    unsigned v2_000 = g1 ? rA0 : U[0];
    unsigned v2_001 = g1 ? rA1 : U[1];
    unsigned v2_010 = g1 ? U[2] : rA0;
    unsigned v2_011 = g1 ? U[3] : rA1;
    unsigned v2_100 = g1 ? rA2 : U[4];
    unsigned v2_101 = g1 ? rA3 : U[5];
    unsigned v2_110 = g1 ? U[6] : rA2;
    unsigned v2_111 = g1 ? U[7] : rA3;
    // butterfly stage B (xor 16, toggles g0): send c2 == !g0
    unsigned rB0 = (unsigned)__shfl_xor((int)(g0 ? v2_000 : v2_010), 16);
    unsigned rB1 = (unsigned)__shfl_xor((int)(g0 ? v2_001 : v2_011), 16);
    unsigned rB2 = (unsigned)__shfl_xor((int)(g0 ? v2_100 : v2_110), 16);
    unsigned rB3 = (unsigned)__shfl_xor((int)(g0 ? v2_101 : v2_111), 16);
    // T[kk][m] = keys {32kk+8g+2m, +1}: m<2 -> kept-if-!g0, m>=2 -> kept-if-g0
    u32x4 t0v, t1v;
    t0v[0] = g0 ? rB0 : v2_000;
    t0v[1] = g0 ? rB1 : v2_001;
    t0v[2] = g0 ? v2_010 : rB0;
    t0v[3] = g0 ? v2_011 : rB1;
    t1v[0] = g0 ? rB2 : v2_100;
    t1v[1] = g0 ? rB3 : v2_101;
    t1v[2] = g0 ? v2_110 : rB2;
    t1v[3] = g0 ? v2_111 : rB3;
    bf16x8 pb0 = __builtin_bit_cast(bf16x8, t0v);  // B-frag P^T, kv-slice kk=0
    bf16x8 pb1 = __builtin_bit_cast(bf16x8, t1v);  // kk=1

    // PV swapped: oacc[n] += V^T-frag(dh rows n*16+lr) * P^T-frag
#pragma unroll
    for (int kk = 0; kk < 2; ++kk) {
      const bf16x8 pb = kk ? pb1 : pb0;
#pragma unroll
      for (int n = 0; n < 4; ++n) {
        const int r = n * 16 + lr;
        const int sl = (r * 8 + kk * 4 + g) ^ (r & 7);
        bf16x8 av = *(const bf16x8*)(&Vs[buf][sl * 8]);
        oacc[n] = __builtin_amdgcn_mfma_f32_16x16x32_bf16(av, pb, oacc[n], 0, 0, 0);
      }
    }
    __syncthreads();                         // prefetch landed + LDS safe to overwrite
    buf ^= 1;
  }

  if (u < 32) {
    // split block: write unnormalized partials (bf16) + (m,l)
    const int pr = G * 1024 + (qt - 16) * 64 + w * 16 + lr;
    bf16* oprow = OP + (size_t)(spl * 32768 + pr) * 64;
#pragma unroll
    for (int n = 0; n < 4; ++n) {
      bf16x4 o4;
#pragma unroll
      for (int i = 0; i < 4; ++i) o4[i] = (bf16)oacc[n][i];
      *(bf16x4*)(oprow + n * 16 + g * 4) = o4;
    }
    if (lane < 16) ML[spl * 32768 + pr] = make_float2(m_i, l_i);
  } else {
    const float li = 1.f / l_i;
    bf16* zrow = Z + ((size_t)(b * 2048 + qg) * 16 + hh) * 64;
#pragma unroll
    for (int n = 0; n < 4; ++n) {
      bf16x4 o4;
#pragma unroll
      for (int i = 0; i < 4; ++i) o4[i] = (bf16)(oacc[n][i] * li);
      *(bf16x4*)(zrow + n * 16 + g * 4) = o4;  // dh = n*16 + 4g + i
    }
  }
}

// ---------------- combine split partials into Z (rows q >= 1024 of each (b,h)) --------
__global__ __launch_bounds__(256)
void combine_kernel(const bf16* __restrict__ OP, const float2* __restrict__ ML,
                    bf16* __restrict__ Z) {
  const int id = blockIdx.x * 256 + threadIdx.x;   // 262144 = 32768 rows x 8 chunks
  const int pr = id >> 3, d8 = id & 7;
  const float2 ml0 = ML[pr], ml1 = ML[32768 + pr];
  const float m = fmaxf(ml0.x, ml1.x);
  const float w0 = __expf(ml0.x - m), w1 = __expf(ml1.x - m);
  const float inv = 1.f / (ml0.y * w0 + ml1.y * w1);
  const bf16x8 a = *(const bf16x8*)(OP + (size_t)pr * 64 + d8 * 8);
  const bf16x8 c = *(const bf16x8*)(OP + ((size_t)32768 + pr) * 64 + d8 * 8);
  bf16x8 o;
#pragma unroll
  for (int j = 0; j < 8; ++j)
    o[j] = (bf16)(((float)a[j] * w0 + (float)c[j] * w1) * inv);
  const int bh = pr >> 10, qr = pr & 1023;
  const int bb = bh >> 4, hq = bh & 15;
  *(bf16x8*)(Z + (((size_t)(bb * 2048 + 1024 + qr)) * 16 + hq) * 64 + d8 * 8) = o;
}

// ---------------- launcher ----------------
extern "C" void kernel_launch(void* const* d_in, const int* in_sizes, int n_in,
                              void* d_out, int out_size, void* d_ws, size_t ws_size,
                              hipStream_t stream) {
  const float* x  = (const float*)d_in[0];
  const float* WQ = (const float*)d_in[1];
  const float* WK = (const float*)d_in[2];
  const float* WV = (const float*)d_in[3];
  const float* WO = (const float*)d_in[4];
  const float* bQ = (const float*)d_in[5];
  const float* bK = (const float*)d_in[6];
  const float* bV = (const float*)d_in[7];
  const float* bO = (const float*)d_in[8];
  float* out = (float*)d_out;

  char* ws = (char*)d_ws;
  bf16* xb    = (bf16*)(ws);                        // 8 MB  [4096,1024]   (reused: OP)
  bf16* Wqkv  = (bf16*)(ws + (8u << 20));           // 6 MB  [3072,1024]   (reused: ML)
  bf16* Wo2   = (bf16*)(ws + (14u << 20));          // 2 MB  [1024,1024]
  bf16* Qb    = (bf16*)(ws + (16u << 20));          // 8 MB  [B,H,S,DH]
  bf16* Kb    = (bf16*)(ws + (24u << 20));          // 8 MB  [B,H,S,DH]
  bf16* Vtb   = (bf16*)(ws + (32u << 20));          // 8 MB  [B,H,DH,S]
  bf16* Zb    = (bf16*)(ws + (40u << 20));          // 8 MB  [4096,1024]
  float* biasq = (float*)(ws + (48u << 20));        // 12 KB [3072]
  // attn partials overlay regions consumed before attn runs (stream-ordered):
  bf16* OP    = (bf16*)(ws);                        // 8 MB  [2][32768][64] bf16
  float2* ML  = (float2*)(ws + (8u << 20));         // 0.5MB [2][32768] (m,l)

  castx_kernel<<<2048, 256, 0, stream>>>(x, xb);
  prep_kernel<<<2048, 256, 0, stream>>>(WQ, WK, WV, WO, bQ, bK, bV, Wqkv, Wo2, biasq);
  gemm_bt<0><<<dim3(32, 24), 256, 0, stream>>>(xb, Wqkv, biasq, Qb, Kb, Vtb, nullptr,
                                               4096, 3072, 1024);
  attn_kernel<<<1536, 256, 0, stream>>>(Qb, Kb, Vtb, Zb, OP, ML);
  combine_kernel<<<1024, 256, 0, stream>>>(OP, ML, Zb);
  gemm_bt<1><<<dim3(32, 8), 256, 0, stream>>>(Zb, Wo2, bO, nullptr, nullptr, nullptr, out,
                                              4096, 1024, 1024);
}

// Round 8
// 207.366 us; speedup vs baseline: 1.1760x; 1.0683x over previous
//
#include <hip/hip_runtime.h>

// ---------------- types ----------------
typedef __bf16 bf16;
typedef __bf16 bf16x4 __attribute__((ext_vector_type(4)));
typedef __bf16 bf16x8 __attribute__((ext_vector_type(8)));
typedef float f32x4 __attribute__((ext_vector_type(4)));
typedef unsigned u32x4 __attribute__((ext_vector_type(4)));

#define AS1C(p) ((const __attribute__((address_space(1))) void*)(p))
#define AS3(p)  ((__attribute__((address_space(3))) void*)(p))

__device__ __forceinline__ void gld16(const bf16* gsrc, bf16* ldst) {
  // async global->LDS, 16 bytes/lane; LDS dest must be wave-uniform base (HW adds lane*16)
  __builtin_amdgcn_global_load_lds(AS1C(gsrc), AS3(ldst), 16, 0, 0);
}

// B=2, S=2048, D=1024, H=16, DH=64; M = B*S = 4096

// ---------------- cast x to bf16 ----------------
__global__ void castx_kernel(const float* __restrict__ x, bf16* __restrict__ xb) {
  const int n4 = (4096 * 1024) / 4;
  for (int i = blockIdx.x * blockDim.x + threadIdx.x; i < n4; i += gridDim.x * blockDim.x) {
    float4 v = ((const float4*)x)[i];
    bf16x4 o;
    o[0] = (bf16)v.x; o[1] = (bf16)v.y; o[2] = (bf16)v.z; o[3] = (bf16)v.w;
    ((bf16x4*)xb)[i] = o;
  }
}

// ---------------- prep weights: Wqkv (Q pre-scaled 1/8), Wo2 transpose, scaled biases ----------------
__global__ void prep_kernel(const float* __restrict__ WQ, const float* __restrict__ WK,
                            const float* __restrict__ WV, const float* __restrict__ WO,
                            const float* __restrict__ bQ, const float* __restrict__ bK,
                            const float* __restrict__ bV,
                            bf16* __restrict__ Wqkv, bf16* __restrict__ Wo2,
                            float* __restrict__ biasq) {
  const int WN = 1024 * 1024;
  const int total = 4 * WN + 3072;
  for (int i = blockIdx.x * blockDim.x + threadIdx.x; i < total; i += gridDim.x * blockDim.x) {
    if (i < WN) {
      Wqkv[i] = (bf16)(WQ[i] * 0.125f);          // fold 1/sqrt(DH) into Q
    } else if (i < 2 * WN) {
      Wqkv[i] = (bf16)WK[i - WN];
    } else if (i < 3 * WN) {
      Wqkv[i] = (bf16)WV[i - 2 * WN];
    } else if (i < 4 * WN) {
      int j = i - 3 * WN;                         // W_O flat [H][D][DH]
      int hh = j >> 16, r = j & 65535, d = r >> 6, dh = r & 63;
      Wo2[d * 1024 + hh * 64 + dh] = (bf16)WO[j]; // Wo2[d][h*64+dh]
    } else {
      int n = i - 4 * WN;
      biasq[n] = (n < 1024) ? bQ[n] * 0.125f : (n < 2048) ? bK[n - 1024] : bV[n - 2048];
    }
  }
}

// ---------------- GEMM C[M,N] = A[M,K] * Bw[N,K]^T  (bf16 in, f32 acc) ----------------
// v2: double-buffered LDS (BK=64), ONE barrier per K-step (barrier -> issue prefetch
// -> compute: stage(t+1) flies under compute(t), drained at next barrier's vmcnt(0)),
// involution XOR-swizzled staging+reads (attn-proven: slot=(row*8+c)^(row&7) kills the
// 16-way stride-128B bank conflict), XCD-chunked 1D block decode (T1).
// MODE 0: QKV projection -> scatter Q[B,H,S,DH], K[B,H,S,DH], Vt[B,H,DH,S] (bf16, +bias)
// MODE 1: out projection -> Co[M,N] f32 (+bias)
template <int MODE>
__global__ __launch_bounds__(256, 2)
void gemm_bt(const bf16* __restrict__ A, const bf16* __restrict__ Bw,
             const float* __restrict__ bias,
             bf16* __restrict__ Qo, bf16* __restrict__ Ko, bf16* __restrict__ Vt,
             float* __restrict__ Co, int M, int N, int K) {
  __shared__ bf16 As[2][8192];               // [buf][128 rows][64 cols], swizzled chunks
  __shared__ bf16 Bs[2][8192];
  const int tid = threadIdx.x;
  const int lane = tid & 63, w = tid >> 6;
  const int wr = w >> 1, wc = w & 1;
  const int g = lane >> 4, lr = lane & 15;
  // XCD-chunked decode: each XCD owns a contiguous run of tiles (M-major)
  const int perx = gridDim.x >> 3;
  const int tile = (blockIdx.x & 7) * perx + (blockIdx.x >> 3);
  const int brow = (tile & 31) * 128, bcol = (tile >> 5) * 128;

  // linear LDS dest + involution-swizzled global source (chunk u receives logical
  // chunk u ^ ((u>>3)&7)); read side applies the same involution.
  auto stage = [&](int k0, int bufi) {
#pragma unroll
    for (int it = 0; it < 4; ++it) {
      const int cb = (it * 4 + w) * 64;      // wave-uniform chunk base
      const int u = cb + lane;
      const int lc = u ^ ((u >> 3) & 7);
      const int row = lc >> 3, c8 = (lc & 7) * 8;
      gld16(A + (size_t)(brow + row) * K + k0 + c8, &As[bufi][cb * 8]);
      gld16(Bw + (size_t)(bcol + row) * K + k0 + c8, &Bs[bufi][cb * 8]);
    }
  };

  f32x4 acc[4][4] = {};
  stage(0, 0);
  const int nstep = K >> 6;

  for (int t = 0; t < nstep; ++t) {
    __syncthreads();                          // stage(t) landed; prior buf reads done
    if (t + 1 < nstep) stage((t + 1) << 6, (t + 1) & 1);   // prefetch under compute
    const bf16* as = As[t & 1];
    const bf16* bs = Bs[t & 1];
#pragma unroll
    for (int kk = 0; kk < 2; ++kk) {
      bf16x8 af[4], bfm[4];
#pragma unroll
      for (int m = 0; m < 4; ++m) {
        const int row = wr * 64 + m * 16 + lr;
        const int sl = (row * 8 + kk * 4 + g) ^ (lr & 7);
        af[m] = *(const bf16x8*)(as + sl * 8);
      }
#pragma unroll
      for (int n = 0; n < 4; ++n) {
        const int row = wc * 64 + n * 16 + lr;
        const int sl = (row * 8 + kk * 4 + g) ^ (lr & 7);
        bfm[n] = *(const bf16x8*)(bs + sl * 8);
      }
#pragma unroll
      for (int m = 0; m < 4; ++m)
#pragma unroll
        for (int n = 0; n < 4; ++n)
          acc[m][n] = __builtin_amdgcn_mfma_f32_16x16x32_bf16(af[m], bfm[n], acc[m][n], 0, 0, 0);
    }
  }

  const int row0 = brow + wr * 64;
  const int col0 = bcol + wc * 64;
#pragma unroll
  for (int m = 0; m < 4; ++m) {
#pragma unroll
    for (int n = 0; n < 4; ++n) {
      const int nidx = col0 + n * 16 + lr;
      f32x4 v = acc[m][n];
      const float bs = bias[nidx];
      if (MODE == 0) {
        const int stream = nidx >> 10;        // 0=Q 1=K 2=V (uniform per 16-lane group)
        const int j = nidx & 1023;
        const int hh = j >> 6, dh = j & 63;
        const int r0 = row0 + m * 16 + g * 4; // token row base; i = 0..3 consecutive
        const int b = r0 >> 11;
        const int p0 = r0 & 2047;
        if (stream == 2) {
          bf16x4 vv;
#pragma unroll
          for (int i = 0; i < 4; ++i) vv[i] = (bf16)(v[i] + bs);
          *(bf16x4*)(Vt + ((size_t)(b * 16 + hh) * 64 + dh) * 2048 + p0) = vv;
        } else {
          bf16* dst = (stream == 0) ? Qo : Ko;
#pragma unroll
          for (int i = 0; i < 4; ++i)
            dst[((size_t)(b * 16 + hh) * 2048 + (p0 + i)) * 64 + dh] = (bf16)(v[i] + bs);
        }
      } else {
#pragma unroll
        for (int i = 0; i < 4; ++i) {
          const int r = row0 + m * 16 + g * 4 + i;
          Co[(size_t)r * 1024 + nidx] = v[i] + bs;
        }
      }
    }
  }
}

// ---------------- causal flash attention (v5: swapped-operand + selective KV-split) ----
// grid 1536 flat. xcd = blk&7; s2 = blk>>3 (0..191); Gl = s2&3; u = s2>>2 (0..47);
// G = (b,h) = Gl*8 + xcd  (4 groups per XCD, all their blocks XCD-local).
// u<32: SPLIT block for qt = 31-(u>>1), spl = u&1: covers t in [0,mid) or [mid,qt+1),
//       mid = (qt+2)>>1; writes UNNORMALIZED partials OP[spl] (bf16) + ML[spl] (m,l).
// u>=32: UNSPLIT block qt = 47-u (<=15): full range, writes normalized Z directly.
__global__ __launch_bounds__(256, 4)
void attn_kernel(const bf16* __restrict__ Qm, const bf16* __restrict__ Km,
                 const bf16* __restrict__ Vm, bf16* __restrict__ Z,
                 bf16* __restrict__ OP, float2* __restrict__ ML) {
  const int nblk = blockIdx.x;
  const int xcd = nblk & 7, s2 = nblk >> 3;
  const int Gl = s2 & 3, u = s2 >> 2;        // u in [0,48)
  const int G = Gl * 8 + xcd;                // (b,h) group 0..31
  const int hh = G & 15, b = G >> 4;
  const int lane = threadIdx.x & 63, w = threadIdx.x >> 6;
  const int g = lane >> 4, lr = lane & 15;
  const bool g0 = g & 1, g1 = (g >> 1) & 1;

  int qt, t0, t1, spl;
  if (u < 32) {
    qt = 31 - (u >> 1); spl = u & 1;
    const int T = qt + 1, mid = (T + 1) >> 1;
    t0 = spl ? mid : 0; t1 = spl ? T : mid;
  } else {
    qt = 47 - u; spl = -1; t0 = 0; t1 = qt + 1;
  }

  __shared__ bf16 Ks[2][4096];               // [buf][64 kv][64 dh], swizzled 16B chunks
  __shared__ bf16 Vs[2][4096];               // [buf][64 dh][64 kv], swizzled 16B chunks

  const bf16* Qb = Qm + (size_t)G * 2048 * 64;
  const bf16* Kb = Km + (size_t)G * 2048 * 64;
  const bf16* Vb = Vm + (size_t)G * 64 * 2048;

  auto stage = [&](int kv0, int bufi) {
#pragma unroll
    for (int it = 0; it < 2; ++it) {
      const int cb = w * 128 + it * 64;      // wave-uniform chunk base
      const int uu = cb + lane;
      const int lc = uu ^ ((uu >> 3) & 7);
      const int row = lc >> 3, c8 = (lc & 7) * 8;
      gld16(Kb + (size_t)(kv0 + row) * 64 + c8, &Ks[bufi][cb * 8]);
      gld16(Vb + (size_t)row * 2048 + kv0 + c8, &Vs[bufi][cb * 8]);
    }
  };

  const int q0w = qt * 64 + w * 16;
  const int qg = q0w + lr;                   // this lane's q row (swapped layout: col=q=lr)

  bf16x8 aq[2];                              // Q[q=lr][k-slice g] — serves as B-fragment
#pragma unroll
  for (int kk = 0; kk < 2; ++kk)
    aq[kk] = *(const bf16x8*)(Qb + (size_t)qg * 64 + kk * 32 + g * 8);

  float m_i = -1e30f, l_i = 0.f;
  f32x4 oacc[4] = {};                        // oacc[n]: O^T rows dh = n*16+4g+i, col q=lr

  int buf = 0;
  stage(t0 * 64, 0);
  __syncthreads();

  for (int t = t0; t < t1; ++t) {
    if (t + 1 < t1) stage((t + 1) * 64, buf ^ 1);  // prefetch next tile
    const int kv0 = t * 64;

    // QK^T swapped: s[n] rows = keys n*16+4g+i, col = q = lr
    f32x4 s[4] = {};
#pragma unroll
    for (int kk = 0; kk < 2; ++kk) {
#pragma unroll
      for (int n = 0; n < 4; ++n) {
        const int r = n * 16 + lr;
        const int sl = (r * 8 + kk * 4 + g) ^ (r & 7);
        bf16x8 bk = *(const bf16x8*)(&Ks[buf][sl * 8]);
        s[n] = __builtin_amdgcn_mfma_f32_16x16x32_bf16(bk, aq[kk], s[n], 0, 0, 0);
      }
    }
    if (t == qt) {                           // causal mask on diagonal tile
#pragma unroll
      for (int n = 0; n < 4; ++n)
#pragma unroll
        for (int i = 0; i < 4; ++i)
          if (kv0 + n * 16 + g * 4 + i > qg) s[n][i] = -1e9f;
    }

    // in-lane softmax for q = lr (16 keys/lane, cross-g via 2 shfl)
    float tm = fmaxf(fmaxf(fmaxf(s[0][0], s[0][1]), fmaxf(s[0][2], s[0][3])),
                     fmaxf(fmaxf(s[1][0], s[1][1]), fmaxf(s[1][2], s[1][3])));
    tm = fmaxf(tm, fmaxf(fmaxf(fmaxf(s[2][0], s[2][1]), fmaxf(s[2][2], s[2][3])),
                         fmaxf(fmaxf(s[3][0], s[3][1]), fmaxf(s[3][2], s[3][3]))));
    tm = fmaxf(tm, __shfl_xor(tm, 16));
    tm = fmaxf(tm, __shfl_xor(tm, 32));
    const float mn = fmaxf(m_i, tm);
    const float al = __expf(m_i - mn);
    m_i = mn;
#pragma unroll
    for (int n = 0; n < 4; ++n)
#pragma unroll
      for (int i = 0; i < 4; ++i) s[n][i] = __expf(s[n][i] - mn);
    float ts = ((s[0][0] + s[0][1]) + (s[0][2] + s[0][3])) +
               ((s[1][0] + s[1][1]) + (s[1][2] + s[1][3])) +
               ((s[2][0] + s[2][1]) + (s[2][2] + s[2][3])) +
               ((s[3][0] + s[3][1]) + (s[3][2] + s[3][3]));
    ts += __shfl_xor(ts, 16);
    ts += __shfl_xor(ts, 32);
    l_i = l_i * al + ts;
#pragma unroll
    for (int n = 0; n < 4; ++n)
#pragma unroll
      for (int i = 0; i < 4; ++i) oacc[n][i] *= al;

    // pack P to bf16 pairs: U[n*2+h] = keys {16n+4g+2h, +1} (key-pair c = 8n+2g+h)
    unsigned U[8];
#pragma unroll
    for (int n = 0; n < 4; ++n)
#pragma unroll
      for (int h = 0; h < 2; ++h) {
        unsigned lo = (unsigned)__builtin_bit_cast(unsigned short, (bf16)s[n][2 * h]);
        unsigned hi = (unsigned)__builtin_bit_cast(unsigned short, (bf16)s[n][2 * h + 1]);
        U[n * 2 + h] = lo | (hi << 16);
      }
    // butterfly stage A (xor 32, toggles g1): send slots with n&1 == !g1
    unsigned rA0 = (unsigned)__shfl_xor((int)(g1 ? U[0] : U[2]), 32);
    unsigned rA1 = (unsigned)__shfl_xor((int)(g1 ? U[1] : U[3]), 32);
    unsigned rA2 = (unsigned)__shfl_xor((int)(g1 ? U[4] : U[6]), 32);
    unsigned rA3 = (unsigned)__shfl_xor((int)(g1 ? U[5] : U[7]), 32);
    // V2[c4][c2][c0]: c2==g1 -> kept U[(2*c4+g1)*2+c0]; else received rA[2*c4+c0]
    unsigned v2_000 = g1 ? rA0 : U[0];
    unsigned v2_001 = g1 ? rA1 : U[1];
    unsigned v2_010 = g1 ? U[2] : rA0;
    unsigned v2_011 = g1 ? U[3] : rA1;
    unsigned v2_100 = g1 ? rA2 : U[4];
    unsigned v2_101 = g1 ? rA3 : U[5];
    unsigned v2_110 = g1 ? U[6] : rA2;
    unsigned v2_111 = g1 ? U[7] : rA3;
    // butterfly stage B (xor 16, toggles g0): send c2 == !g0
    unsigned rB0 = (unsigned)__shfl_xor((int)(g0 ? v2_000 : v2_010), 16);
    unsigned rB1 = (unsigned)__shfl_xor((int)(g0 ? v2_001 : v2_011), 16);
    unsigned rB2 = (unsigned)__shfl_xor((int)(g0 ? v2_100 : v2_110), 16);
    unsigned rB3 = (unsigned)__shfl_xor((int)(g0 ? v2_101 : v2_111), 16);
    // T[kk][m] = keys {32kk+8g+2m, +1}: m<2 -> kept-if-!g0, m>=2 -> kept-if-g0
    u32x4 t0v, t1v;
    t0v[0] = g0 ? rB0 : v2_000;
    t0v[1] = g0 ? rB1 : v2_001;
    t0v[2] = g0 ? v2_010 : rB0;
    t0v[3] = g0 ? v2_011 : rB1;
    t1v[0] = g0 ? rB2 : v2_100;
    t1v[1] = g0 ? rB3 : v2_101;
    t1v[2] = g0 ? v2_110 : rB2;
    t1v[3] = g0 ? v2_111 : rB3;
    bf16x8 pb0 = __builtin_bit_cast(bf16x8, t0v);  // B-frag P^T, kv-slice kk=0
    bf16x8 pb1 = __builtin_bit_cast(bf16x8, t1v);  // kk=1

    // PV swapped: oacc[n] += V^T-frag(dh rows n*16+lr) * P^T-frag
#pragma unroll
    for (int kk = 0; kk < 2; ++kk) {
      const bf16x8 pb = kk ? pb1 : pb0;
#pragma unroll
      for (int n = 0; n < 4; ++n) {
        const int r = n * 16 + lr;
        const int sl = (r * 8 + kk * 4 + g) ^ (r & 7);
        bf16x8 av = *(const bf16x8*)(&Vs[buf][sl * 8]);
        oacc[n] = __builtin_amdgcn_mfma_f32_16x16x32_bf16(av, pb, oacc[n], 0, 0, 0);
      }
    }
    __syncthreads();                         // prefetch landed + LDS safe to overwrite
    buf ^= 1;
  }

  if (u < 32) {
    // split block: write unnormalized partials (bf16) + (m,l)
    const int pr = G * 1024 + (qt - 16) * 64 + w * 16 + lr;
    bf16* oprow = OP + (size_t)(spl * 32768 + pr) * 64;
#pragma unroll
    for (int n = 0; n < 4; ++n) {
      bf16x4 o4;
#pragma unroll
      for (int i = 0; i < 4; ++i) o4[i] = (bf16)oacc[n][i];
      *(bf16x4*)(oprow + n * 16 + g * 4) = o4;
    }
    if (lane < 16) ML[spl * 32768 + pr] = make_float2(m_i, l_i);
  } else {
    const float li = 1.f / l_i;
    bf16* zrow = Z + ((size_t)(b * 2048 + qg) * 16 + hh) * 64;
#pragma unroll
    for (int n = 0; n < 4; ++n) {
      bf16x4 o4;
#pragma unroll
      for (int i = 0; i < 4; ++i) o4[i] = (bf16)(oacc[n][i] * li);
      *(bf16x4*)(zrow + n * 16 + g * 4) = o4;  // dh = n*16 + 4g + i
    }
  }
}

// ---------------- combine split partials into Z (rows q >= 1024 of each (b,h)) --------
__global__ __launch_bounds__(256)
void combine_kernel(const bf16* __restrict__ OP, const float2* __restrict__ ML,
                    bf16* __restrict__ Z) {
  const int id = blockIdx.x * 256 + threadIdx.x;   // 262144 = 32768 rows x 8 chunks
  const int pr = id >> 3, d8 = id & 7;
  const float2 ml0 = ML[pr], ml1 = ML[32768 + pr];
  const float m = fmaxf(ml0.x, ml1.x);
  const float w0 = __expf(ml0.x - m), w1 = __expf(ml1.x - m);
  const float inv = 1.f / (ml0.y * w0 + ml1.y * w1);
  const bf16x8 a = *(const bf16x8*)(OP + (size_t)pr * 64 + d8 * 8);
  const bf16x8 c = *(const bf16x8*)(OP + ((size_t)32768 + pr) * 64 + d8 * 8);
  bf16x8 o;
#pragma unroll
  for (int j = 0; j < 8; ++j)
    o[j] = (bf16)(((float)a[j] * w0 + (float)c[j] * w1) * inv);
  const int bh = pr >> 10, qr = pr & 1023;
  const int bb = bh >> 4, hq = bh & 15;
  *(bf16x8*)(Z + (((size_t)(bb * 2048 + 1024 + qr)) * 16 + hq) * 64 + d8 * 8) = o;
}

// ---------------- launcher ----------------
extern "C" void kernel_launch(void* const* d_in, const int* in_sizes, int n_in,
                              void* d_out, int out_size, void* d_ws, size_t ws_size,
                              hipStream_t stream) {
  const float* x  = (const float*)d_in[0];
  const float* WQ = (const float*)d_in[1];
  const float* WK = (const float*)d_in[2];
  const float* WV = (const float*)d_in[3];
  const float* WO = (const float*)d_in[4];
  const float* bQ = (const float*)d_in[5];
  const float* bK = (const float*)d_in[6];
  const float* bV = (const float*)d_in[7];
  const float* bO = (const float*)d_in[8];
  float* out = (float*)d_out;

  char* ws = (char*)d_ws;
  bf16* xb    = (bf16*)(ws);                        // 8 MB  [4096,1024]   (reused: OP)
  bf16* Wqkv  = (bf16*)(ws + (8u << 20));           // 6 MB  [3072,1024]   (reused: ML)
  bf16* Wo2   = (bf16*)(ws + (14u << 20));          // 2 MB  [1024,1024]
  bf16* Qb    = (bf16*)(ws + (16u << 20));          // 8 MB  [B,H,S,DH]
  bf16* Kb    = (bf16*)(ws + (24u << 20));          // 8 MB  [B,H,S,DH]
  bf16* Vtb   = (bf16*)(ws + (32u << 20));          // 8 MB  [B,H,DH,S]
  bf16* Zb    = (bf16*)(ws + (40u << 20));          // 8 MB  [4096,1024]
  float* biasq = (float*)(ws + (48u << 20));        // 12 KB [3072]
  // attn partials overlay regions consumed before attn runs (stream-ordered):
  bf16* OP    = (bf16*)(ws);                        // 8 MB  [2][32768][64] bf16
  float2* ML  = (float2*)(ws + (8u << 20));         // 0.5MB [2][32768] (m,l)

  castx_kernel<<<2048, 256, 0, stream>>>(x, xb);
  prep_kernel<<<2048, 256, 0, stream>>>(WQ, WK, WV, WO, bQ, bK, bV, Wqkv, Wo2, biasq);
  gemm_bt<0><<<768, 256, 0, stream>>>(xb, Wqkv, biasq, Qb, Kb, Vtb, nullptr,
                                      4096, 3072, 1024);
  attn_kernel<<<1536, 256, 0, stream>>>(Qb, Kb, Vtb, Zb, OP, ML);
  combine_kernel<<<1024, 256, 0, stream>>>(OP, ML, Zb);
  gemm_bt<1><<<256, 256, 0, stream>>>(Zb, Wo2, bO, nullptr, nullptr, nullptr, out,
                                      4096, 1024, 1024);
}

// Round 9
// 205.840 us; speedup vs baseline: 1.1847x; 1.0074x over previous
//
#include <hip/hip_runtime.h>

// ---------------- types ----------------
typedef __bf16 bf16;
typedef __bf16 bf16x4 __attribute__((ext_vector_type(4)));
typedef __bf16 bf16x8 __attribute__((ext_vector_type(8)));
typedef float f32x4 __attribute__((ext_vector_type(4)));
typedef unsigned u32x4 __attribute__((ext_vector_type(4)));
typedef unsigned u32x2 __attribute__((ext_vector_type(2)));

#define AS1C(p) ((const __attribute__((address_space(1))) void*)(p))
#define AS3(p)  ((__attribute__((address_space(3))) void*)(p))

__device__ __forceinline__ void gld16(const bf16* gsrc, bf16* ldst) {
  // async global->LDS, 16 bytes/lane; LDS dest must be wave-uniform base (HW adds lane*16)
  __builtin_amdgcn_global_load_lds(AS1C(gsrc), AS3(ldst), 16, 0, 0);
}

// B=2, S=2048, D=1024, H=16, DH=64; M = B*S = 4096
// Softmax runs in the LOG2 domain: Q (and b_Q) pre-scaled by 0.125*log2(e), so
// QK^T scores are log2-scaled; exp2f == v_exp_f32 (no pre-multiply per element).
#define QSCALE 0.18033688011112042f   // 0.125 * log2(e)

// ---------------- fused cast x + weight prep (one dispatch) ----------------
__global__ void prep_all(const float* __restrict__ x,
                         const float* __restrict__ WQ, const float* __restrict__ WK,
                         const float* __restrict__ WV, const float* __restrict__ WO,
                         const float* __restrict__ bQ, const float* __restrict__ bK,
                         const float* __restrict__ bV,
                         bf16* __restrict__ xb, bf16* __restrict__ Wqkv,
                         bf16* __restrict__ Wo2, float* __restrict__ biasq) {
  const int X4 = (4096 * 1024) / 4;          // float4 items of x
  const int WN = 1024 * 1024;
  const int total = X4 + 4 * WN + 3072;
  for (int i = blockIdx.x * blockDim.x + threadIdx.x; i < total; i += gridDim.x * blockDim.x) {
    if (i < X4) {
      float4 v = ((const float4*)x)[i];
      bf16x4 o;
      o[0] = (bf16)v.x; o[1] = (bf16)v.y; o[2] = (bf16)v.z; o[3] = (bf16)v.w;
      ((bf16x4*)xb)[i] = o;
    } else {
      int j = i - X4;
      if (j < WN) {
        Wqkv[j] = (bf16)(WQ[j] * QSCALE);        // fold 1/sqrt(DH) * log2e into Q
      } else if (j < 2 * WN) {
        Wqkv[j] = (bf16)WK[j - WN];
      } else if (j < 3 * WN) {
        Wqkv[j] = (bf16)WV[j - 2 * WN];
      } else if (j < 4 * WN) {
        int k = j - 3 * WN;                      // W_O flat [H][D][DH]
        int hh = k >> 16, r = k & 65535, d = r >> 6, dh = r & 63;
        Wo2[d * 1024 + hh * 64 + dh] = (bf16)WO[k];
      } else {
        int n = j - 4 * WN;
        biasq[n] = (n < 1024) ? bQ[n] * QSCALE : (n < 2048) ? bK[n - 1024] : bV[n - 2048];
      }
    }
  }
}

// ---------------- GEMM C[M,N] = A[M,K] * Bw[N,K]^T  (bf16 in, f32 acc) ----------------
// v2: double-buffered LDS (BK=64), ONE barrier per K-step, involution XOR-swizzled
// staging+reads, XCD-chunked 1D block decode.
// MODE 0: QKV projection -> scatter Q[B,H,S,DH], K[B,H,S,DH], Vt[B,H,DH,S] (bf16, +bias)
// MODE 1: out projection -> Co[M,N] f32 (+bias)
template <int MODE>
__global__ __launch_bounds__(256, 2)
void gemm_bt(const bf16* __restrict__ A, const bf16* __restrict__ Bw,
             const float* __restrict__ bias,
             bf16* __restrict__ Qo, bf16* __restrict__ Ko, bf16* __restrict__ Vt,
             float* __restrict__ Co, int M, int N, int K) {
  __shared__ bf16 As[2][8192];               // [buf][128 rows][64 cols], swizzled chunks
  __shared__ bf16 Bs[2][8192];
  const int tid = threadIdx.x;
  const int lane = tid & 63, w = tid >> 6;
  const int wr = w >> 1, wc = w & 1;
  const int g = lane >> 4, lr = lane & 15;
  const int perx = gridDim.x >> 3;
  const int tile = (blockIdx.x & 7) * perx + (blockIdx.x >> 3);
  const int brow = (tile & 31) * 128, bcol = (tile >> 5) * 128;

  auto stage = [&](int k0, int bufi) {
#pragma unroll
    for (int it = 0; it < 4; ++it) {
      const int cb = (it * 4 + w) * 64;      // wave-uniform chunk base
      const int u = cb + lane;
      const int lc = u ^ ((u >> 3) & 7);
      const int row = lc >> 3, c8 = (lc & 7) * 8;
      gld16(A + (size_t)(brow + row) * K + k0 + c8, &As[bufi][cb * 8]);
      gld16(Bw + (size_t)(bcol + row) * K + k0 + c8, &Bs[bufi][cb * 8]);
    }
  };

  f32x4 acc[4][4] = {};
  stage(0, 0);
  const int nstep = K >> 6;

  for (int t = 0; t < nstep; ++t) {
    __syncthreads();                          // stage(t) landed; prior buf reads done
    if (t + 1 < nstep) stage((t + 1) << 6, (t + 1) & 1);   // prefetch under compute
    const bf16* as = As[t & 1];
    const bf16* bs = Bs[t & 1];
#pragma unroll
    for (int kk = 0; kk < 2; ++kk) {
      bf16x8 af[4], bfm[4];
#pragma unroll
      for (int m = 0; m < 4; ++m) {
        const int row = wr * 64 + m * 16 + lr;
        const int sl = (row * 8 + kk * 4 + g) ^ (lr & 7);
        af[m] = *(const bf16x8*)(as + sl * 8);
      }
#pragma unroll
      for (int n = 0; n < 4; ++n) {
        const int row = wc * 64 + n * 16 + lr;
        const int sl = (row * 8 + kk * 4 + g) ^ (lr & 7);
        bfm[n] = *(const bf16x8*)(bs + sl * 8);
      }
#pragma unroll
      for (int m = 0; m < 4; ++m)
#pragma unroll
        for (int n = 0; n < 4; ++n)
          acc[m][n] = __builtin_amdgcn_mfma_f32_16x16x32_bf16(af[m], bfm[n], acc[m][n], 0, 0, 0);
    }
  }

  const int row0 = brow + wr * 64;
  const int col0 = bcol + wc * 64;
#pragma unroll
  for (int m = 0; m < 4; ++m) {
#pragma unroll
    for (int n = 0; n < 4; ++n) {
      const int nidx = col0 + n * 16 + lr;
      f32x4 v = acc[m][n];
      const float bs = bias[nidx];
      if (MODE == 0) {
        const int stream = nidx >> 10;        // 0=Q 1=K 2=V (uniform per 16-lane group)
        const int j = nidx & 1023;
        const int hh = j >> 6, dh = j & 63;
        const int r0 = row0 + m * 16 + g * 4; // token row base; i = 0..3 consecutive
        const int b = r0 >> 11;
        const int p0 = r0 & 2047;
        if (stream == 2) {
          bf16x4 vv;
#pragma unroll
          for (int i = 0; i < 4; ++i) vv[i] = (bf16)(v[i] + bs);
          *(bf16x4*)(Vt + ((size_t)(b * 16 + hh) * 64 + dh) * 2048 + p0) = vv;
        } else {
          bf16* dst = (stream == 0) ? Qo : Ko;
#pragma unroll
          for (int i = 0; i < 4; ++i)
            dst[((size_t)(b * 16 + hh) * 2048 + (p0 + i)) * 64 + dh] = (bf16)(v[i] + bs);
        }
      } else {
#pragma unroll
        for (int i = 0; i < 4; ++i) {
          const int r = row0 + m * 16 + g * 4 + i;
          Co[(size_t)r * 1024 + nidx] = v[i] + bs;
        }
      }
    }
  }
}

// ---------------- causal flash attention (v6: log2-domain softmax, defer-max, --------
// permlane butterfly). Structure as v5: swapped QK^T/PV, selective KV-split, grid 1536.
__global__ __launch_bounds__(256, 4)
void attn_kernel(const bf16* __restrict__ Qm, const bf16* __restrict__ Km,
                 const bf16* __restrict__ Vm, bf16* __restrict__ Z,
                 bf16* __restrict__ OP, float2* __restrict__ ML) {
  const int nblk = blockIdx.x;
  const int xcd = nblk & 7, s2 = nblk >> 3;
  const int Gl = s2 & 3, u = s2 >> 2;        // u in [0,48)
  const int G = Gl * 8 + xcd;                // (b,h) group 0..31
  const int hh = G & 15, b = G >> 4;
  const int lane = threadIdx.x & 63, w = threadIdx.x >> 6;
  const int g = lane >> 4, lr = lane & 15;
  const bool g0 = g & 1, g1 = (g >> 1) & 1;

  int qt, t0, t1, spl;
  if (u < 32) {
    qt = 31 - (u >> 1); spl = u & 1;
    const int T = qt + 1, mid = (T + 1) >> 1;
    t0 = spl ? mid : 0; t1 = spl ? T : mid;
  } else {
    qt = 47 - u; spl = -1; t0 = 0; t1 = qt + 1;
  }

  __shared__ bf16 Ks[2][4096];               // [buf][64 kv][64 dh], swizzled 16B chunks
  __shared__ bf16 Vs[2][4096];               // [buf][64 dh][64 kv], swizzled 16B chunks

  const bf16* Qb = Qm + (size_t)G * 2048 * 64;
  const bf16* Kb = Km + (size_t)G * 2048 * 64;
  const bf16* Vb = Vm + (size_t)G * 64 * 2048;

  auto stage = [&](int kv0, int bufi) {
#pragma unroll
    for (int it = 0; it < 2; ++it) {
      const int cb = w * 128 + it * 64;      // wave-uniform chunk base
      const int uu = cb + lane;
      const int lc = uu ^ ((uu >> 3) & 7);
      const int row = lc >> 3, c8 = (lc & 7) * 8;
      gld16(Kb + (size_t)(kv0 + row) * 64 + c8, &Ks[bufi][cb * 8]);
      gld16(Vb + (size_t)row * 2048 + kv0 + c8, &Vs[bufi][cb * 8]);
    }
  };

  const int q0w = qt * 64 + w * 16;
  const int qg = q0w + lr;                   // this lane's q row (swapped layout: col=q=lr)

  bf16x8 aq[2];                              // Q[q=lr][k-slice g] — serves as B-fragment
#pragma unroll
  for (int kk = 0; kk < 2; ++kk)
    aq[kk] = *(const bf16x8*)(Qb + (size_t)qg * 64 + kk * 32 + g * 8);

  float m_i = -1e30f, l_i = 0.f;
  f32x4 oacc[4] = {};                        // oacc[n]: O^T rows dh = n*16+4g+i, col q=lr

  int buf = 0;
  stage(t0 * 64, 0);
  __syncthreads();

  for (int t = t0; t < t1; ++t) {
    if (t + 1 < t1) stage((t + 1) * 64, buf ^ 1);  // prefetch next tile
    const int kv0 = t * 64;

    // QK^T swapped: s[n] rows = keys n*16+4g+i, col = q = lr  (log2-scaled scores)
    f32x4 s[4] = {};
#pragma unroll
    for (int kk = 0; kk < 2; ++kk) {
#pragma unroll
      for (int n = 0; n < 4; ++n) {
        const int r = n * 16 + lr;
        const int sl = (r * 8 + kk * 4 + g) ^ (r & 7);
        bf16x8 bk = *(const bf16x8*)(&Ks[buf][sl * 8]);
        s[n] = __builtin_amdgcn_mfma_f32_16x16x32_bf16(bk, aq[kk], s[n], 0, 0, 0);
      }
    }
    if (t == qt) {                           // causal mask on diagonal tile
#pragma unroll
      for (int n = 0; n < 4; ++n)
#pragma unroll
        for (int i = 0; i < 4; ++i)
          if (kv0 + n * 16 + g * 4 + i > qg) s[n][i] = -1e9f;
    }

    // in-lane softmax for q = lr (16 keys/lane, cross-g via 2 shfl); defer-max (T13)
    float tm = fmaxf(fmaxf(fmaxf(s[0][0], s[0][1]), fmaxf(s[0][2], s[0][3])),
                     fmaxf(fmaxf(s[1][0], s[1][1]), fmaxf(s[1][2], s[1][3])));
    tm = fmaxf(tm, fmaxf(fmaxf(fmaxf(s[2][0], s[2][1]), fmaxf(s[2][2], s[2][3])),
                         fmaxf(fmaxf(s[3][0], s[3][1]), fmaxf(s[3][2], s[3][3]))));
    tm = fmaxf(tm, __shfl_xor(tm, 16));
    tm = fmaxf(tm, __shfl_xor(tm, 32));
    if (!__all(tm <= m_i + 12.f)) {          // rescale only when max grew materially
      const float mn = fmaxf(m_i, tm);
      const float al = exp2f(m_i - mn);
      m_i = mn;
      l_i *= al;
#pragma unroll
      for (int n = 0; n < 4; ++n)
#pragma unroll
        for (int i = 0; i < 4; ++i) oacc[n][i] *= al;
    }
#pragma unroll
    for (int n = 0; n < 4; ++n)
#pragma unroll
      for (int i = 0; i < 4; ++i) s[n][i] = exp2f(s[n][i] - m_i);  // P in [0, 2^12]
    float ts = ((s[0][0] + s[0][1]) + (s[0][2] + s[0][3])) +
               ((s[1][0] + s[1][1]) + (s[1][2] + s[1][3])) +
               ((s[2][0] + s[2][1]) + (s[2][2] + s[2][3])) +
               ((s[3][0] + s[3][1]) + (s[3][2] + s[3][3]));
    ts += __shfl_xor(ts, 16);
    ts += __shfl_xor(ts, 32);
    l_i += ts;

    // pack P to bf16 pairs: U[n*2+h] = key-pair c = 8n+2g+h (bits c4c3=n, c2c1=g, c0=h)
    unsigned U[8];
#pragma unroll
    for (int n = 0; n < 4; ++n)
#pragma unroll
      for (int h = 0; h < 2; ++h) {
        unsigned lo = (unsigned)__builtin_bit_cast(unsigned short, (bf16)s[n][2 * h]);
        unsigned hi = (unsigned)__builtin_bit_cast(unsigned short, (bf16)s[n][2 * h + 1]);
        U[n * 2 + h] = lo | (hi << 16);
      }
    // redistribute to PV B-frag layout: target c4=kk, c3=g1, c2=g0, c1c0=m
    unsigned v2_000, v2_001, v2_010, v2_011, v2_100, v2_101, v2_110, v2_111;
#if __has_builtin(__builtin_amdgcn_permlane32_swap)
    // stage A: one half-swap per (c4,h) pair -> both outputs usable (c2=0 and c2=1 slots)
    {
      u32x2 pA0 = __builtin_amdgcn_permlane32_swap(U[0], U[2], false, false);
      u32x2 pA1 = __builtin_amdgcn_permlane32_swap(U[1], U[3], false, false);
      u32x2 pA2 = __builtin_amdgcn_permlane32_swap(U[4], U[6], false, false);
      u32x2 pA3 = __builtin_amdgcn_permlane32_swap(U[5], U[7], false, false);
      v2_000 = pA0[0]; v2_010 = pA0[1];
      v2_001 = pA1[0]; v2_011 = pA1[1];
      v2_100 = pA2[0]; v2_110 = pA2[1];
      v2_101 = pA3[0]; v2_111 = pA3[1];
    }
#else
    {
      unsigned rA0 = (unsigned)__shfl_xor((int)(g1 ? U[0] : U[2]), 32);
      unsigned rA1 = (unsigned)__shfl_xor((int)(g1 ? U[1] : U[3]), 32);
      unsigned rA2 = (unsigned)__shfl_xor((int)(g1 ? U[4] : U[6]), 32);
      unsigned rA3 = (unsigned)__shfl_xor((int)(g1 ? U[5] : U[7]), 32);
      v2_000 = g1 ? rA0 : U[0];
      v2_001 = g1 ? rA1 : U[1];
      v2_010 = g1 ? U[2] : rA0;
      v2_011 = g1 ? U[3] : rA1;
      v2_100 = g1 ? rA2 : U[4];
      v2_101 = g1 ? rA3 : U[5];
      v2_110 = g1 ? U[6] : rA2;
      v2_111 = g1 ? U[7] : rA3;
    }
#endif
    u32x4 t0v, t1v;
#if __has_builtin(__builtin_amdgcn_permlane16_swap)
    {
      u32x2 pB0 = __builtin_amdgcn_permlane16_swap(v2_000, v2_010, false, false);
      u32x2 pB1 = __builtin_amdgcn_permlane16_swap(v2_001, v2_011, false, false);
      u32x2 pB2 = __builtin_amdgcn_permlane16_swap(v2_100, v2_110, false, false);
      u32x2 pB3 = __builtin_amdgcn_permlane16_swap(v2_101, v2_111, false, false);
      t0v[0] = pB0[0]; t0v[2] = pB0[1];
      t0v[1] = pB1[0]; t0v[3] = pB1[1];
      t1v[0] = pB2[0]; t1v[2] = pB2[1];
      t1v[1] = pB3[0]; t1v[3] = pB3[1];
    }
#else
    {
      unsigned rB0 = (unsigned)__shfl_xor((int)(g0 ? v2_000 : v2_010), 16);
      unsigned rB1 = (unsigned)__shfl_xor((int)(g0 ? v2_001 : v2_011), 16);
      unsigned rB2 = (unsigned)__shfl_xor((int)(g0 ? v2_100 : v2_110), 16);
      unsigned rB3 = (unsigned)__shfl_xor((int)(g0 ? v2_101 : v2_111), 16);
      t0v[0] = g0 ? rB0 : v2_000;
      t0v[1] = g0 ? rB1 : v2_001;
      t0v[2] = g0 ? v2_010 : rB0;
      t0v[3] = g0 ? v2_011 : rB1;
      t1v[0] = g0 ? rB2 : v2_100;
      t1v[1] = g0 ? rB3 : v2_101;
      t1v[2] = g0 ? v2_110 : rB2;
      t1v[3] = g0 ? v2_111 : rB3;
    }
#endif
    bf16x8 pb0 = __builtin_bit_cast(bf16x8, t0v);  // B-frag P^T, kv-slice kk=0
    bf16x8 pb1 = __builtin_bit_cast(bf16x8, t1v);  // kk=1

    // PV swapped: oacc[n] += V^T-frag(dh rows n*16+lr) * P^T-frag
#pragma unroll
    for (int kk = 0; kk < 2; ++kk) {
      const bf16x8 pb = kk ? pb1 : pb0;
#pragma unroll
      for (int n = 0; n < 4; ++n) {
        const int r = n * 16 + lr;
        const int sl = (r * 8 + kk * 4 + g) ^ (r & 7);
        bf16x8 av = *(const bf16x8*)(&Vs[buf][sl * 8]);
        oacc[n] = __builtin_amdgcn_mfma_f32_16x16x32_bf16(av, pb, oacc[n], 0, 0, 0);
      }
    }
    __syncthreads();                         // prefetch landed + LDS safe to overwrite
    buf ^= 1;
  }

  if (u < 32) {
    // split block: write unnormalized partials (bf16) + (m,l) [m in log2 domain]
    const int pr = G * 1024 + (qt - 16) * 64 + w * 16 + lr;
    bf16* oprow = OP + (size_t)(spl * 32768 + pr) * 64;
#pragma unroll
    for (int n = 0; n < 4; ++n) {
      bf16x4 o4;
#pragma unroll
      for (int i = 0; i < 4; ++i) o4[i] = (bf16)oacc[n][i];
      *(bf16x4*)(oprow + n * 16 + g * 4) = o4;
    }
    if (lane < 16) ML[spl * 32768 + pr] = make_float2(m_i, l_i);
  } else {
    const float li = 1.f / l_i;
    bf16* zrow = Z + ((size_t)(b * 2048 + qg) * 16 + hh) * 64;
#pragma unroll
    for (int n = 0; n < 4; ++n) {
      bf16x4 o4;
#pragma unroll
      for (int i = 0; i < 4; ++i) o4[i] = (bf16)(oacc[n][i] * li);
      *(bf16x4*)(zrow + n * 16 + g * 4) = o4;  // dh = n*16 + 4g + i
    }
  }
}

// ---------------- combine split partials into Z (rows q >= 1024 of each (b,h)) --------
__global__ __launch_bounds__(256)
void combine_kernel(const bf16* __restrict__ OP, const float2* __restrict__ ML,
                    bf16* __restrict__ Z) {
  const int id = blockIdx.x * 256 + threadIdx.x;   // 262144 = 32768 rows x 8 chunks
  const int pr = id >> 3, d8 = id & 7;
  const float2 ml0 = ML[pr], ml1 = ML[32768 + pr];
  const float m = fmaxf(ml0.x, ml1.x);
  const float w0 = exp2f(ml0.x - m), w1 = exp2f(ml1.x - m);   // log2-domain maxes
  const float inv = 1.f / (ml0.y * w0 + ml1.y * w1);
  const bf16x8 a = *(const bf16x8*)(OP + (size_t)pr * 64 + d8 * 8);
  const bf16x8 c = *(const bf16x8*)(OP + ((size_t)32768 + pr) * 64 + d8 * 8);
  bf16x8 o;
#pragma unroll
  for (int j = 0; j < 8; ++j)
    o[j] = (bf16)(((float)a[j] * w0 + (float)c[j] * w1) * inv);
  const int bh = pr >> 10, qr = pr & 1023;
  const int bb = bh >> 4, hq = bh & 15;
  *(bf16x8*)(Z + (((size_t)(bb * 2048 + 1024 + qr)) * 16 + hq) * 64 + d8 * 8) = o;
}

// ---------------- launcher ----------------
extern "C" void kernel_launch(void* const* d_in, const int* in_sizes, int n_in,
                              void* d_out, int out_size, void* d_ws, size_t ws_size,
                              hipStream_t stream) {
  const float* x  = (const float*)d_in[0];
  const float* WQ = (const float*)d_in[1];
  const float* WK = (const float*)d_in[2];
  const float* WV = (const float*)d_in[3];
  const float* WO = (const float*)d_in[4];
  const float* bQ = (const float*)d_in[5];
  const float* bK = (const float*)d_in[6];
  const float* bV = (const float*)d_in[7];
  const float* bO = (const float*)d_in[8];
  float* out = (float*)d_out;

  char* ws = (char*)d_ws;
  bf16* xb    = (bf16*)(ws);                        // 8 MB  [4096,1024]   (reused: OP)
  bf16* Wqkv  = (bf16*)(ws + (8u << 20));           // 6 MB  [3072,1024]   (reused: ML)
  bf16* Wo2   = (bf16*)(ws + (14u << 20));          // 2 MB  [1024,1024]
  bf16* Qb    = (bf16*)(ws + (16u << 20));          // 8 MB  [B,H,S,DH]
  bf16* Kb    = (bf16*)(ws + (24u << 20));          // 8 MB  [B,H,S,DH]
  bf16* Vtb   = (bf16*)(ws + (32u << 20));          // 8 MB  [B,H,DH,S]
  bf16* Zb    = (bf16*)(ws + (40u << 20));          // 8 MB  [4096,1024]
  float* biasq = (float*)(ws + (48u << 20));        // 12 KB [3072]
  // attn partials overlay regions consumed before attn runs (stream-ordered):
  bf16* OP    = (bf16*)(ws);                        // 8 MB  [2][32768][64] bf16
  float2* ML  = (float2*)(ws + (8u << 20));         // 0.5MB [2][32768] (m,l)

  prep_all<<<2048, 256, 0, stream>>>(x, WQ, WK, WV, WO, bQ, bK, bV, xb, Wqkv, Wo2, biasq);
  gemm_bt<0><<<768, 256, 0, stream>>>(xb, Wqkv, biasq, Qb, Kb, Vtb, nullptr,
                                      4096, 3072, 1024);
  attn_kernel<<<1536, 256, 0, stream>>>(Qb, Kb, Vtb, Zb, OP, ML);
  combine_kernel<<<1024, 256, 0, stream>>>(OP, ML, Zb);
  gemm_bt<1><<<256, 256, 0, stream>>>(Zb, Wo2, bO, nullptr, nullptr, nullptr, out,
                                      4096, 1024, 1024);
}